// Round 6
// baseline (278.621 us; speedup 1.0000x reference)
//
#include <hip/hip_runtime.h>
#include <math.h>

// PGTAttention fused block, MI355X gfx950. Round 6.
// Change vs r5: qkv GEMM moved to a 256x256 8-wave deep-pipelined kernel
// (T3+T4: counted vmcnt(8) across raw s_barriers, prefetch never drained;
// 64 MFMA/wave between barrier pairs; same HW-verified (row&7)<<4 XOR swizzle
// that measured 0 bank conflicts in r5). Proj GEMM / attention / preps frozen.

typedef unsigned short u16;
typedef unsigned int   u32;
typedef u16   u16x8 __attribute__((ext_vector_type(8)));
typedef __bf16 bf16x8 __attribute__((ext_vector_type(8)));
typedef float f32x4 __attribute__((ext_vector_type(4)));

#define GPTR(p) ((const __attribute__((address_space(1))) void*)(p))
#define LPTR(p) ((__attribute__((address_space(3))) void*)(p))

__device__ __forceinline__ u16 f2bf(float x) {
  u32 u = __float_as_uint(x);
  return (u16)((u + 0x7fffu + ((u >> 16) & 1u)) >> 16);  // RNE
}

__device__ __forceinline__ bf16x8 ld8(const void* p) {
  u16x8 v = *reinterpret_cast<const u16x8*>(p);
  return __builtin_bit_cast(bf16x8, v);
}

// global->LDS direct copy, 16B/lane; LDS dest = wave-uniform base + lane*16.
__device__ __forceinline__ void g2l16(const void* g, void* l) {
  __builtin_amdgcn_global_load_lds(GPTR(g), LPTR(l), 16, 0, 0);
}

// ---------------- elementwise cast f32 -> bf16, 8 elems/thread ----------------
__global__ void cast_bf16_kernel(const float* __restrict__ in, u16* __restrict__ out, int n8) {
  int i = blockIdx.x * 256 + threadIdx.x;
  if (i >= n8) return;
  const float4* p = reinterpret_cast<const float4*>(in) + (size_t)i * 2;
  float4 a = p[0], b = p[1];
  u16x8 v;
  v[0] = f2bf(a.x); v[1] = f2bf(a.y); v[2] = f2bf(a.z); v[3] = f2bf(a.w);
  v[4] = f2bf(b.x); v[5] = f2bf(b.y); v[6] = f2bf(b.z); v[7] = f2bf(b.w);
  reinterpret_cast<u16x8*>(out)[i] = v;
}

// ---------------- transpose + cast: out[c][r] = bf16(in[r][c]), in is R x C f32 -------
__global__ void tcast_kernel(const float* __restrict__ in, u16* __restrict__ out, int R, int C) {
  __shared__ float t[32][33];
  int bx = blockIdx.x * 32, by = blockIdx.y * 32;
  int x = threadIdx.x, y = threadIdx.y;  // (32, 8)
  #pragma unroll
  for (int k = 0; k < 32; k += 8)
    t[y + k][x] = in[(size_t)(by + y + k) * C + (bx + x)];
  __syncthreads();
  #pragma unroll
  for (int k = 0; k < 32; k += 8)
    out[(size_t)(bx + y + k) * R + (by + x)] = f2bf(t[x][y + k]);
}

// ------- V transpose from qkv: out[bh][d][s] = qkv[b][s][4096 + h*256 + d] ----------
__global__ void tv_kernel(const u16* __restrict__ qkv, u16* __restrict__ out) {
  __shared__ u16 t[32][33];
  int bh = blockIdx.z, b = bh >> 3, h = bh & 7;
  const u16* ip = qkv + (size_t)b * 2048 * 6144 + 4096 + h * 256;
  u16* op = out + (size_t)bh * 256 * 2048;
  int bx = blockIdx.x * 32, by = blockIdx.y * 32;  // bx: d, by: s
  int x = threadIdx.x, y = threadIdx.y;
  #pragma unroll
  for (int k = 0; k < 32; k += 8)
    t[y + k][x] = ip[(size_t)(by + y + k) * 6144 + (bx + x)];
  __syncthreads();
  #pragma unroll
  for (int k = 0; k < 32; k += 8)
    op[(size_t)(bx + y + k) * 2048 + (by + x)] = t[x][y + k];
}

// ---------------- 256x256 8-wave deep-pipelined GEMM: C = A[M,K] * Bt[N,K]^T ------------
// 512 thr (8 waves, 2M x 4N; per-wave 128x64 output). BK=64. LDS 128KB (A,B double-buf).
// Pipeline per K-step t: s_barrier(A) [buf (t+1)&1 free] -> issue stage(t+1) (8 gload_lds,
// 16 in flight) -> vmcnt(8) [stage(t) landed; t+1 stays in flight] -> s_barrier(B) ->
// 4 MFMA phases (B-frags once, A-frags per phase; 64 MFMA). vmcnt never 0 mid-loop.
__global__ __launch_bounds__(512, 2) void gemm256_kernel(
    const u16* __restrict__ A, const u16* __restrict__ Bt,
    float* __restrict__ Cf, u16* __restrict__ Cb, int M, int N, int K) {
  __shared__ __align__(16) u16 sA[2][256 * 64];  // 64 KiB
  __shared__ __align__(16) u16 sB[2][256 * 64];  // 64 KiB
  const int tid = threadIdx.x;
  const int lane = tid & 63, w = tid >> 6;
  const int wr = w >> 2, wc = w & 3;
  const int g = lane >> 4, li = lane & 15;
  const int bn = blockIdx.x * 256, bm = blockIdx.y * 256;

  // staging: 32 chunks of 1KB per matrix; wave w owns chunks w*4..w*4+3.
  // LDS dest linear (chunk*1024 + lane*16); source pre-inverse-swizzled (involution).
  const char* aSrc[4]; const char* bSrc[4]; u32 dOff[4];
  #pragma unroll
  for (int j = 0; j < 4; ++j) {
    int chunk = w * 4 + j;
    int o = chunk * 1024 + lane * 16;
    int row = o >> 7;
    int cbs = (o & 127) ^ ((row & 7) << 4);
    aSrc[j] = (const char*)A + (size_t)(bm + row) * K * 2 + cbs;
    bSrc[j] = (const char*)Bt + (size_t)(bn + row) * K * 2 + cbs;
    dOff[j] = (u32)chunk * 1024;
  }

  const f32x4 fz = {0.f, 0.f, 0.f, 0.f};
  f32x4 acc[8][4];
  #pragma unroll
  for (int i = 0; i < 8; ++i)
    #pragma unroll
    for (int j = 0; j < 4; ++j) acc[i][j] = fz;

  const int NT = K >> 6;  // 64-wide K-steps
  // prologue: stage K-step 0 into buf 0
  #pragma unroll
  for (int j = 0; j < 4; ++j) {
    g2l16(aSrc[j], (char*)sA[0] + dOff[j]);
    g2l16(bSrc[j], (char*)sB[0] + dOff[j]);
    aSrc[j] += 128; bSrc[j] += 128;
  }

  for (int t = 0; t < NT; ++t) {
    const int cur = t & 1;
    const bool more = (t + 1 < NT);
    // barrier A: every wave finished reading buf[(t+1)&1] (iteration t-1's phases)
    asm volatile("s_barrier" ::: "memory");
    if (more) {
      #pragma unroll
      for (int j = 0; j < 4; ++j) {
        g2l16(aSrc[j], (char*)sA[cur ^ 1] + dOff[j]);
        g2l16(bSrc[j], (char*)sB[cur ^ 1] + dOff[j]);
        aSrc[j] += 128; bSrc[j] += 128;
      }
      asm volatile("s_waitcnt vmcnt(8)" ::: "memory");  // stage(t) landed; t+1 in flight
    } else {
      asm volatile("s_waitcnt vmcnt(0)" ::: "memory");  // last tile
    }
    asm volatile("s_barrier" ::: "memory");  // B: all waves' staged slices visible

    const char* sAb = (const char*)sA[cur];
    const char* sBb = (const char*)sB[cur];
    // B fragments once per K-step (8 x ds_read_b128)
    bf16x8 bReg[2][4];
    #pragma unroll
    for (int nf = 0; nf < 4; ++nf) {
      int rb = wc * 64 + nf * 16 + li;
      int swz = (rb & 7) << 4;
      const char* base = sBb + rb * 128;
      bReg[0][nf] = ld8(base + ((g * 16) ^ swz));
      bReg[1][nf] = ld8(base + ((64 + g * 16) ^ swz));
    }
    // 4 phases: A-frags for 2 m-rows, then 16 MFMA
    #pragma unroll
    for (int q = 0; q < 4; ++q) {
      bf16x8 aReg[2][2];
      #pragma unroll
      for (int sub = 0; sub < 2; ++sub) {
        int ra = wr * 128 + (2 * q + sub) * 16 + li;
        int swz = (ra & 7) << 4;
        const char* base = sAb + ra * 128;
        aReg[0][sub] = ld8(base + ((g * 16) ^ swz));
        aReg[1][sub] = ld8(base + ((64 + g * 16) ^ swz));
      }
      __builtin_amdgcn_s_setprio(1);
      #pragma unroll
      for (int sub = 0; sub < 2; ++sub)
        #pragma unroll
        for (int nf = 0; nf < 4; ++nf)
          #pragma unroll
          for (int ks = 0; ks < 2; ++ks)
            acc[2 * q + sub][nf] =
                __builtin_amdgcn_mfma_f32_16x16x32_bf16(aReg[ks][sub], bReg[ks][nf],
                                                        acc[2 * q + sub][nf], 0, 0, 0);
      __builtin_amdgcn_s_setprio(0);
    }
  }

  if (Cb) {
    #pragma unroll
    for (int mf = 0; mf < 8; ++mf)
      #pragma unroll
      for (int nf = 0; nf < 4; ++nf)
        #pragma unroll
        for (int r = 0; r < 4; ++r) {
          int gm = bm + wr * 128 + mf * 16 + g * 4 + r;
          int gn = bn + wc * 64 + nf * 16 + li;
          Cb[(size_t)gm * N + gn] = f2bf(acc[mf][nf][r]);
        }
  } else {
    #pragma unroll
    for (int mf = 0; mf < 8; ++mf)
      #pragma unroll
      for (int nf = 0; nf < 4; ++nf)
        #pragma unroll
        for (int r = 0; r < 4; ++r) {
          int gm = bm + wr * 128 + mf * 16 + g * 4 + r;
          int gn = bn + wc * 64 + nf * 16 + li;
          Cf[(size_t)gm * N + gn] = acc[mf][nf][r];
        }
  }
}

// ---------------- 128x128 GEMM (2-barrier), used for proj ----------------
__global__ __launch_bounds__(256) void gemm_bt_kernel(
    const u16* __restrict__ A, const u16* __restrict__ Bt,
    float* __restrict__ Cf, u16* __restrict__ Cb, int M, int N, int K) {
  __shared__ __align__(16) u16 sA[128 * 64];  // 16 KiB
  __shared__ __align__(16) u16 sB[128 * 64];  // 16 KiB
  const int tid = threadIdx.x;
  const int lane = tid & 63, w = tid >> 6;
  const int wr = w >> 1, wc = w & 1;
  const int g = lane >> 4, li = lane & 15;
  const int bn = blockIdx.x * 128, bm = blockIdx.y * 128;

  const char* aSrc[4]; const char* bSrc[4];
  char* aDst[4]; char* bDst[4];
  #pragma unroll
  for (int j = 0; j < 4; ++j) {
    int chunk = w * 4 + j;
    int o = chunk * 1024 + lane * 16;
    int row = o >> 7, cb = o & 127;
    int cbs = cb ^ ((row & 7) << 4);
    aSrc[j] = (const char*)A + (size_t)(bm + row) * K * 2 + cbs;
    bSrc[j] = (const char*)Bt + (size_t)(bn + row) * K * 2 + cbs;
    aDst[j] = (char*)sA + chunk * 1024;
    bDst[j] = (char*)sB + chunk * 1024;
  }
  const char* aRd[2][4]; const char* bRd[2][4];
  #pragma unroll
  for (int ks = 0; ks < 2; ++ks) {
    #pragma unroll
    for (int f = 0; f < 4; ++f) {
      int ra = wr * 64 + f * 16 + li;
      aRd[ks][f] = (const char*)sA + ra * 128 + ((ks * 64 + g * 16) ^ ((ra & 7) << 4));
      int rb = wc * 64 + f * 16 + li;
      bRd[ks][f] = (const char*)sB + rb * 128 + ((ks * 64 + g * 16) ^ ((rb & 7) << 4));
    }
  }

  const f32x4 fz = {0.f, 0.f, 0.f, 0.f};
  f32x4 acc[4][4];
  #pragma unroll
  for (int i = 0; i < 4; ++i)
    #pragma unroll
    for (int j = 0; j < 4; ++j) acc[i][j] = fz;

  for (int k0 = 0; k0 < K; k0 += 64) {
    #pragma unroll
    for (int j = 0; j < 4; ++j) { g2l16(aSrc[j], aDst[j]); g2l16(bSrc[j], bDst[j]); }
    #pragma unroll
    for (int j = 0; j < 4; ++j) { aSrc[j] += 128; bSrc[j] += 128; }
    __syncthreads();
    bf16x8 af[2][4], bfv[2][4];
    #pragma unroll
    for (int ks = 0; ks < 2; ++ks)
      #pragma unroll
      for (int f = 0; f < 4; ++f) { af[ks][f] = ld8(aRd[ks][f]); bfv[ks][f] = ld8(bRd[ks][f]); }
    #pragma unroll
    for (int ks = 0; ks < 2; ++ks)
      #pragma unroll
      for (int mf = 0; mf < 4; ++mf)
        #pragma unroll
        for (int nf = 0; nf < 4; ++nf)
          acc[mf][nf] = __builtin_amdgcn_mfma_f32_16x16x32_bf16(af[ks][mf], bfv[ks][nf], acc[mf][nf], 0, 0, 0);
    __syncthreads();
  }

  if (Cf) {
    #pragma unroll
    for (int mf = 0; mf < 4; ++mf)
      #pragma unroll
      for (int nf = 0; nf < 4; ++nf)
        #pragma unroll
        for (int r = 0; r < 4; ++r) {
          int gm = bm + wr * 64 + mf * 16 + g * 4 + r;
          int gn = bn + wc * 64 + nf * 16 + li;
          Cf[(size_t)gm * N + gn] = acc[mf][nf][r];
        }
  } else {
    #pragma unroll
    for (int mf = 0; mf < 4; ++mf)
      #pragma unroll
      for (int nf = 0; nf < 4; ++nf)
        #pragma unroll
        for (int r = 0; r < 4; ++r) {
          int gm = bm + wr * 64 + mf * 16 + g * 4 + r;
          int gn = bn + wc * 64 + nf * 16 + li;
          Cb[(size_t)gm * N + gn] = f2bf(acc[mf][nf][r]);
        }
  }
}

// ---------------- flash attention + fused PMSNorm (split-k, balanced) ----------------
// Unchanged from r5.
__global__ __launch_bounds__(512, 2) void attn_kernel(
    const u16* __restrict__ qkv, const u16* __restrict__ Vt,
    const float* __restrict__ nw, u16* __restrict__ Mrg) {
  __shared__ __align__(16) char smem[106496];       // 104 KiB
  char* sKb = smem;
  char* sVb = smem + 65536;
  char* sPb = smem + 65536 + 32768;
  float* oex  = (float*)smem;
  float* mlex = (float*)(smem + 65536);

  const int c = blockIdx.x;
  const int bh = c & 15, iu = c >> 4;
  const int b = bh >> 3, h = bh & 7;
  const int tid = threadIdx.x, lane = tid & 63, w = tid >> 6;
  const int kh = w >> 2, wq = w & 3;
  const int g = lane >> 4, li = lane & 15;
  const float MASKV = -30000.0f;
  const float MINIT = -1000.0f;
  const float isc = 1.0f / 64.0f; // 1 / (sqrt(256) * (LAYER_IDX+1))
  const f32x4 fz = {0.f, 0.f, 0.f, 0.f};
  const size_t KADV = (size_t)32 * 6144 * 2;

  #pragma unroll 1
  for (int uu = 0; uu < 2; ++uu) {
    const int qt = uu ? (31 - iu) : iu;
    const int nt = qt + 1;
    const int kvb0 = kh * nt * 32;

    int qrow = qt * 64 + wq * 16 + li;
    const u16* qp = qkv + (size_t)(b * 2048 + qrow) * 6144 + h * 256;
    bf16x8 qf[8];
    #pragma unroll
    for (int c8 = 0; c8 < 8; ++c8) qf[c8] = ld8(qp + c8 * 32 + g * 8);

    const char* kSrc[4]; u32 kDoff[4];
    #pragma unroll
    for (int j = 0; j < 4; ++j) {
      int chunk = wq * 4 + j;
      int o = chunk * 1024 + lane * 16;
      int row = o >> 9, cb = o & 511;
      int cbs = cb ^ ((row & 7) << 4);
      kSrc[j] = (const char*)qkv + ((size_t)(b * 2048 + kvb0 + row) * 6144 + 2048 + h * 256) * 2 + cbs;
      kDoff[j] = chunk * 1024;
    }
    const char* vSrc[4]; char* vDst[4];
    #pragma unroll
    for (int j = 0; j < 4; ++j) {
      int chunk = wq * 4 + j;
      int o = chunk * 1024 + lane * 16;
      int row = o >> 6, cb = o & 63;
      int cbs = cb ^ (((row >> 1) & 3) << 4);
      vSrc[j] = (const char*)Vt + ((size_t)(bh * 256 + row) * 2048 + kvb0) * 2 + cbs;
      vDst[j] = sVb + kh * 16384 + chunk * 1024;
    }

    f32x4 o_[16];
    #pragma unroll
    for (int nf = 0; nf < 16; ++nf) o_[nf] = fz;
    float m_[4] = {MINIT, MINIT, MINIT, MINIT};
    float l_[4] = {0.f, 0.f, 0.f, 0.f};

    {
      char* kb0 = sKb + (kh * 2 + 0) * 16384;
      #pragma unroll
      for (int j = 0; j < 4; ++j) { g2l16(kSrc[j], kb0 + kDoff[j]); kSrc[j] += KADV; }
    }
    asm volatile("s_waitcnt vmcnt(0)" ::: "memory");
    asm volatile("s_barrier" ::: "memory");

    int cur = 0;
    for (int t = 0; t < nt; ++t) {
      const bool more = (t < nt - 1);
      #pragma unroll
      for (int j = 0; j < 4; ++j) { g2l16(vSrc[j], vDst[j]); vSrc[j] += 64; }
      if (more) {
        char* kb = sKb + (kh * 2 + (cur ^ 1)) * 16384;
        #pragma unroll
        for (int j = 0; j < 4; ++j) { g2l16(kSrc[j], kb + kDoff[j]); kSrc[j] += KADV; }
      }

      f32x4 sacc[2];
      const char* kbase = sKb + (kh * 2 + cur) * 16384;
      __builtin_amdgcn_s_setprio(1);
      #pragma unroll
      for (int nf = 0; nf < 2; ++nf) {
        int row = nf * 16 + li;
        int swz = (row & 7) << 4;
        const char* kr = kbase + row * 512;
        f32x4 sa = fz, sb = fz;
        #pragma unroll
        for (int c8 = 0; c8 < 4; ++c8) {
          sa = __builtin_amdgcn_mfma_f32_16x16x32_bf16(qf[c8],     ld8(kr + ((c8 * 64 + g * 16) ^ swz)),       sa, 0, 0, 0);
          sb = __builtin_amdgcn_mfma_f32_16x16x32_bf16(qf[c8 + 4], ld8(kr + (((c8 + 4) * 64 + g * 16) ^ swz)), sb, 0, 0, 0);
        }
        sacc[nf] = sa + sb;
      }
      __builtin_amdgcn_s_setprio(0);

      const int tidx = kh * nt + t;
      const bool diag = (tidx >= 2 * qt);
      float p[2][4], m0[4];
      #pragma unroll
      for (int r = 0; r < 4; ++r) {
        int qr = qt * 64 + wq * 16 + g * 4 + r;
        float a0 = sacc[0][r] * isc;
        float a1 = sacc[1][r] * isc;
        if (diag) {
          if (tidx * 32 + li > qr) a0 = MASKV;
          if (tidx * 32 + 16 + li > qr) a1 = MASKV;
        }
        p[0][r] = a0; p[1][r] = a1;
        m0[r] = fmaxf(a0, a1);
      }
      bool need = (m0[0] > m_[0] + 8.f) || (m0[1] > m_[1] + 8.f) ||
                  (m0[2] > m_[2] + 8.f) || (m0[3] > m_[3] + 8.f);
      if (__any(need)) {
        #pragma unroll
        for (int r = 0; r < 4; ++r) {
          float mx = m0[r];
          mx = fmaxf(mx, __shfl_xor(mx, 1));
          mx = fmaxf(mx, __shfl_xor(mx, 2));
          mx = fmaxf(mx, __shfl_xor(mx, 4));
          mx = fmaxf(mx, __shfl_xor(mx, 8));
          float mn = fmaxf(m_[r], mx);
          float sc = __expf(m_[r] - mn);
          l_[r] *= sc; m_[r] = mn;
          #pragma unroll
          for (int nf = 0; nf < 16; ++nf) o_[nf][r] *= sc;
        }
      }
      #pragma unroll
      for (int r = 0; r < 4; ++r) {
        float e0 = __expf(p[0][r] - m_[r]);
        float e1 = __expf(p[1][r] - m_[r]);
        p[0][r] = e0; p[1][r] = e1;
        l_[r] += e0 + e1;
      }

      if (more) asm volatile("s_waitcnt vmcnt(4)" ::: "memory");
      else      asm volatile("s_waitcnt vmcnt(0)" ::: "memory");
      asm volatile("s_barrier" ::: "memory");

      char* sPw = sPb + kh * 4096 + wq * 1024;
      #pragma unroll
      for (int r = 0; r < 4; ++r) {
        int row = g * 4 + r;
        int swz = ((row >> 1) & 3) << 4;
        #pragma unroll
        for (int nf = 0; nf < 2; ++nf)
          *(u16*)(sPw + row * 64 + (((nf * 16 + li) * 2) ^ swz)) = f2bf(p[nf][r]);
      }
      asm volatile("s_waitcnt lgkmcnt(0)" ::: "memory");
      __builtin_amdgcn_sched_barrier(0);

      __builtin_amdgcn_s_setprio(1);
      {
        const char* vb = sVb + kh * 16384;
        bf16x8 pa = ld8(sPw + li * 64 + ((g * 16) ^ (((li >> 1) & 3) << 4)));
        #pragma unroll
        for (int nf = 0; nf < 16; ++nf) {
          int row = nf * 16 + li;
          bf16x8 vf = ld8(vb + row * 64 + ((g * 16) ^ (((row >> 1) & 3) << 4)));
          o_[nf] = __builtin_amdgcn_mfma_f32_16x16x32_bf16(pa, vf, o_[nf], 0, 0, 0);
        }
      }
      __builtin_amdgcn_s_setprio(0);

      asm volatile("s_barrier" ::: "memory");
      if (more) asm volatile("s_waitcnt vmcnt(0)" ::: "memory");
      cur ^= 1;
    }

    if (kh == 1) {
      #pragma unroll
      for (int nf = 0; nf < 16; ++nf)
        *(f32x4*)(oex + wq * 4096 + nf * 256 + lane * 4) = o_[nf];
      #pragma unroll
      for (int r = 0; r < 4; ++r) {
        mlex[wq * 512 + r * 64 + lane] = l_[r];
        mlex[wq * 512 + 256 + r * 64 + lane] = m_[r];
      }
    }
    __syncthreads();
    if (kh == 0) {
      float aw[4], bw[4], inv_l[4];
      #pragma unroll
      for (int r = 0; r < 4; ++r) {
        float mB = mlex[wq * 512 + 256 + r * 64 + lane];
        float lB = mlex[wq * 512 + r * 64 + lane];
        float mm = fmaxf(m_[r], mB);
        aw[r] = __expf(m_[r] - mm);
        bw[r] = __expf(mB - mm);
        float lr = l_[r] * aw[r] + lB * bw[r];
        lr += __shfl_xor(lr, 1);
        lr += __shfl_xor(lr, 2);
        lr += __shfl_xor(lr, 4);
        lr += __shfl_xor(lr, 8);
        inv_l[r] = 1.0f / lr;
      }
      #pragma unroll
      for (int nf = 0; nf < 16; ++nf) {
        f32x4 ob = *(f32x4*)(oex + wq * 4096 + nf * 256 + lane * 4);
        #pragma unroll
        for (int r = 0; r < 4; ++r)
          o_[nf][r] = o_[nf][r] * aw[r] + ob[r] * bw[r];
      }
      #pragma unroll
      for (int r = 0; r < 4; ++r) {
        float ss = 0.f;
        #pragma unroll
        for (int nf = 0; nf < 16; ++nf) {
          float v = o_[nf][r] * inv_l[r];
          ss += v * v;
        }
        ss += __shfl_xor(ss, 1);
        ss += __shfl_xor(ss, 2);
        ss += __shfl_xor(ss, 4);
        ss += __shfl_xor(ss, 8);
        float rms = rsqrtf(ss * (1.0f / 256.0f) + 1e-5f);
        int row = qt * 64 + wq * 16 + g * 4 + r;
        #pragma unroll
        for (int nf = 0; nf < 16; ++nf) {
          int d = nf * 16 + li;
          float v = o_[nf][r] * inv_l[r] * rms * nw[d];
          Mrg[((size_t)(b * 2048 + row)) * 2048 + h * 256 + d] = f2bf(v);
        }
      }
    }
    __syncthreads();
  }
}

extern "C" void kernel_launch(void* const* d_in, const int* in_sizes, int n_in,
                              void* d_out, int out_size, void* d_ws, size_t ws_size,
                              hipStream_t stream) {
  const float* hs  = (const float*)d_in[0];   // [2,2048,2048]
  const float* wat = (const float*)d_in[1];   // [2048,6144]
  const float* wpr = (const float*)d_in[2];   // [2048,2048]
  const float* nw  = (const float*)d_in[3];   // [256]
  float* out = (float*)d_out;                 // [2,2048,2048] f32

  char* ws = (char*)d_ws;
  u16* Xb   = (u16*)(ws + 0);                    // 16 MiB  [4096][2048] bf16
  u16* Wp_t = (u16*)(ws + (16u << 20));          //  8 MiB  [2048][2048] bf16 (w_proj^T)
  u16* Qkv  = (u16*)(ws + (24u << 20));          // 48 MiB  [4096][6144] bf16
  u16* Vt   = (u16*)(ws + (72u << 20));          // 16 MiB  [16][256][2048] bf16
  u16* Mrg  = Xb;                                // aliases Xb (dead after GEMM1)
  u16* Wa_t = (u16*)d_out;                       // 24 MiB scratch (w_attn^T [6144][2048])

  dim3 t328(32, 8);
  cast_bf16_kernel<<<4096, 256, 0, stream>>>(hs, Xb, 1048576);
  tcast_kernel<<<dim3(192, 64), t328, 0, stream>>>(wat, Wa_t, 2048, 6144);
  tcast_kernel<<<dim3(64, 64), t328, 0, stream>>>(wpr, Wp_t, 2048, 2048);
  gemm256_kernel<<<dim3(24, 16), 512, 0, stream>>>(Xb, Wa_t, nullptr, Qkv, 4096, 6144, 2048);
  tv_kernel<<<dim3(8, 64, 16), t328, 0, stream>>>(Qkv, Vt);
  attn_kernel<<<256, 512, 0, stream>>>(Qkv, Vt, nw, Mrg);
  gemm_bt_kernel<<<dim3(16, 32), 256, 0, stream>>>(Mrg, Wp_t, out, nullptr, 4096, 2048, 2048);
  (void)in_sizes; (void)n_in; (void)out_size; (void)ws_size;
}

// Round 7
// 251.546 us; speedup vs baseline: 1.1076x; 1.1076x over previous
//
#include <hip/hip_runtime.h>
#include <math.h>

// PGTAttention fused block, MI355X gfx950. Round 7.
// Change vs r6: qkv GEMM retiled 256x256 -> 256x192 (8 waves, 1 block/CU) so the
// grid becomes 16x32 = 512 = exactly 2 full dispatch rounds over 256 CUs (r6's 384
// blocks @ 1/CU gave 75% packing; per-active-CU throughput was 3.6 TF -- structure
// kept, packing fixed). Pipeline identical to r6: counted vmcnt(7) across raw
// s_barriers, prefetch never drained. Proj GEMM / attention / preps frozen.

typedef unsigned short u16;
typedef unsigned int   u32;
typedef u16   u16x8 __attribute__((ext_vector_type(8)));
typedef __bf16 bf16x8 __attribute__((ext_vector_type(8)));
typedef float f32x4 __attribute__((ext_vector_type(4)));

#define GPTR(p) ((const __attribute__((address_space(1))) void*)(p))
#define LPTR(p) ((__attribute__((address_space(3))) void*)(p))

__device__ __forceinline__ u16 f2bf(float x) {
  u32 u = __float_as_uint(x);
  return (u16)((u + 0x7fffu + ((u >> 16) & 1u)) >> 16);  // RNE
}

__device__ __forceinline__ bf16x8 ld8(const void* p) {
  u16x8 v = *reinterpret_cast<const u16x8*>(p);
  return __builtin_bit_cast(bf16x8, v);
}

// global->LDS direct copy, 16B/lane; LDS dest = wave-uniform base + lane*16.
__device__ __forceinline__ void g2l16(const void* g, void* l) {
  __builtin_amdgcn_global_load_lds(GPTR(g), LPTR(l), 16, 0, 0);
}

// ---------------- elementwise cast f32 -> bf16, 8 elems/thread ----------------
__global__ void cast_bf16_kernel(const float* __restrict__ in, u16* __restrict__ out, int n8) {
  int i = blockIdx.x * 256 + threadIdx.x;
  if (i >= n8) return;
  const float4* p = reinterpret_cast<const float4*>(in) + (size_t)i * 2;
  float4 a = p[0], b = p[1];
  u16x8 v;
  v[0] = f2bf(a.x); v[1] = f2bf(a.y); v[2] = f2bf(a.z); v[3] = f2bf(a.w);
  v[4] = f2bf(b.x); v[5] = f2bf(b.y); v[6] = f2bf(b.z); v[7] = f2bf(b.w);
  reinterpret_cast<u16x8*>(out)[i] = v;
}

// ---------------- transpose + cast: out[c][r] = bf16(in[r][c]), in is R x C f32 -------
__global__ void tcast_kernel(const float* __restrict__ in, u16* __restrict__ out, int R, int C) {
  __shared__ float t[32][33];
  int bx = blockIdx.x * 32, by = blockIdx.y * 32;
  int x = threadIdx.x, y = threadIdx.y;  // (32, 8)
  #pragma unroll
  for (int k = 0; k < 32; k += 8)
    t[y + k][x] = in[(size_t)(by + y + k) * C + (bx + x)];
  __syncthreads();
  #pragma unroll
  for (int k = 0; k < 32; k += 8)
    out[(size_t)(bx + y + k) * R + (by + x)] = f2bf(t[x][y + k]);
}

// ------- V transpose from qkv: out[bh][d][s] = qkv[b][s][4096 + h*256 + d] ----------
__global__ void tv_kernel(const u16* __restrict__ qkv, u16* __restrict__ out) {
  __shared__ u16 t[32][33];
  int bh = blockIdx.z, b = bh >> 3, h = bh & 7;
  const u16* ip = qkv + (size_t)b * 2048 * 6144 + 4096 + h * 256;
  u16* op = out + (size_t)bh * 256 * 2048;
  int bx = blockIdx.x * 32, by = blockIdx.y * 32;  // bx: d, by: s
  int x = threadIdx.x, y = threadIdx.y;
  #pragma unroll
  for (int k = 0; k < 32; k += 8)
    t[y + k][x] = ip[(size_t)(by + y + k) * 6144 + (bx + x)];
  __syncthreads();
  #pragma unroll
  for (int k = 0; k < 32; k += 8)
    op[(size_t)(bx + y + k) * 2048 + (by + x)] = t[x][y + k];
}

// -------- 256x192 8-wave pipelined GEMM (qkv): C = A[M,K] * Bt[N,K]^T, bf16 out -------
// 512 thr (8 waves, 2M x 4N; per-wave 128x48). BK=64. LDS 112KB (A 2x32KB, B 2x24KB).
// Per K-step t: s_barrier [buf (t+1)&1 free] -> issue stage(t+1) (7 gload_lds/wave,
// 14 in flight) -> vmcnt(7) [stage(t) landed; t+1 stays in flight] -> s_barrier ->
// B-frags (6 ds_read_b128) + 4 phases {4 A ds_reads, 12 MFMA setprio-wrapped}.
__global__ __launch_bounds__(512, 2) void gemm256_kernel(
    const u16* __restrict__ A, const u16* __restrict__ Bt,
    u16* __restrict__ Cb, int M, int N, int K) {
  __shared__ __align__(16) u16 sA[2][256 * 64];  // 64 KiB
  __shared__ __align__(16) u16 sB[2][192 * 64];  // 48 KiB
  const int tid = threadIdx.x;
  const int lane = tid & 63, w = tid >> 6;
  const int wr = w >> 2, wc = w & 3;
  const int g = lane >> 4, li = lane & 15;
  const int bn = blockIdx.x * 192, bm = blockIdx.y * 256;

  // staging: A = 32 chunks of 1KB, B = 24 chunks; 56 total, 7 per wave.
  // LDS dest linear; source pre-inverse-swizzled ((row&7)<<4 involution).
  const char* src[7]; u32 dOff[7]; bool isA[7];
  #pragma unroll
  for (int j = 0; j < 7; ++j) {
    int chunk = w * 7 + j;
    bool a = chunk < 32;
    int lc = a ? chunk : chunk - 32;
    int o = lc * 1024 + lane * 16;
    int row = o >> 7;
    int cbs = (o & 127) ^ ((row & 7) << 4);
    src[j] = a ? (const char*)A + (size_t)(bm + row) * K * 2 + cbs
               : (const char*)Bt + (size_t)(bn + row) * K * 2 + cbs;
    dOff[j] = (u32)lc * 1024;
    isA[j] = a;
  }

  const f32x4 fz = {0.f, 0.f, 0.f, 0.f};
  f32x4 acc[8][3];
  #pragma unroll
  for (int i = 0; i < 8; ++i)
    #pragma unroll
    for (int j = 0; j < 3; ++j) acc[i][j] = fz;

  const int NT = K >> 6;  // 64-wide K-steps
  // prologue: stage K-step 0 into buf 0
  #pragma unroll
  for (int j = 0; j < 7; ++j) {
    g2l16(src[j], (isA[j] ? (char*)sA[0] : (char*)sB[0]) + dOff[j]);
    src[j] += 128;
  }

  for (int t = 0; t < NT; ++t) {
    const int cur = t & 1;
    const bool more = (t + 1 < NT);
    // barrier: every wave finished reading buf[(t+1)&1] (iteration t-1)
    asm volatile("s_barrier" ::: "memory");
    if (more) {
      #pragma unroll
      for (int j = 0; j < 7; ++j) {
        g2l16(src[j], (isA[j] ? (char*)sA[cur ^ 1] : (char*)sB[cur ^ 1]) + dOff[j]);
        src[j] += 128;
      }
      asm volatile("s_waitcnt vmcnt(7)" ::: "memory");  // stage(t) landed; t+1 in flight
    } else {
      asm volatile("s_waitcnt vmcnt(0)" ::: "memory");
    }
    asm volatile("s_barrier" ::: "memory");  // all waves' staged slices visible

    const char* sAb = (const char*)sA[cur];
    const char* sBb = (const char*)sB[cur];
    // B fragments once per K-step (6 x ds_read_b128)
    bf16x8 bReg[2][3];
    #pragma unroll
    for (int nf = 0; nf < 3; ++nf) {
      int rb = wc * 48 + nf * 16 + li;
      int swz = (rb & 7) << 4;
      const char* base = sBb + rb * 128;
      bReg[0][nf] = ld8(base + ((g * 16) ^ swz));
      bReg[1][nf] = ld8(base + ((64 + g * 16) ^ swz));
    }
    // 4 phases: A-frags for 2 m-rows, then 12 MFMA
    #pragma unroll
    for (int q = 0; q < 4; ++q) {
      bf16x8 aReg[2][2];
      #pragma unroll
      for (int sub = 0; sub < 2; ++sub) {
        int ra = wr * 128 + (2 * q + sub) * 16 + li;
        int swz = (ra & 7) << 4;
        const char* base = sAb + ra * 128;
        aReg[0][sub] = ld8(base + ((g * 16) ^ swz));
        aReg[1][sub] = ld8(base + ((64 + g * 16) ^ swz));
      }
      __builtin_amdgcn_s_setprio(1);
      #pragma unroll
      for (int sub = 0; sub < 2; ++sub)
        #pragma unroll
        for (int nf = 0; nf < 3; ++nf)
          #pragma unroll
          for (int ks = 0; ks < 2; ++ks)
            acc[2 * q + sub][nf] =
                __builtin_amdgcn_mfma_f32_16x16x32_bf16(aReg[ks][sub], bReg[ks][nf],
                                                        acc[2 * q + sub][nf], 0, 0, 0);
      __builtin_amdgcn_s_setprio(0);
    }
  }

  #pragma unroll
  for (int mf = 0; mf < 8; ++mf)
    #pragma unroll
    for (int nf = 0; nf < 3; ++nf)
      #pragma unroll
      for (int r = 0; r < 4; ++r) {
        int gm = bm + wr * 128 + mf * 16 + g * 4 + r;
        int gn = bn + wc * 48 + nf * 16 + li;
        Cb[(size_t)gm * N + gn] = f2bf(acc[mf][nf][r]);
      }
}

// ---------------- 128x128 GEMM (2-barrier), used for proj ----------------
__global__ __launch_bounds__(256) void gemm_bt_kernel(
    const u16* __restrict__ A, const u16* __restrict__ Bt,
    float* __restrict__ Cf, u16* __restrict__ Cb, int M, int N, int K) {
  __shared__ __align__(16) u16 sA[128 * 64];  // 16 KiB
  __shared__ __align__(16) u16 sB[128 * 64];  // 16 KiB
  const int tid = threadIdx.x;
  const int lane = tid & 63, w = tid >> 6;
  const int wr = w >> 1, wc = w & 1;
  const int g = lane >> 4, li = lane & 15;
  const int bn = blockIdx.x * 128, bm = blockIdx.y * 128;

  const char* aSrc[4]; const char* bSrc[4];
  char* aDst[4]; char* bDst[4];
  #pragma unroll
  for (int j = 0; j < 4; ++j) {
    int chunk = w * 4 + j;
    int o = chunk * 1024 + lane * 16;
    int row = o >> 7, cb = o & 127;
    int cbs = cb ^ ((row & 7) << 4);
    aSrc[j] = (const char*)A + (size_t)(bm + row) * K * 2 + cbs;
    bSrc[j] = (const char*)Bt + (size_t)(bn + row) * K * 2 + cbs;
    aDst[j] = (char*)sA + chunk * 1024;
    bDst[j] = (char*)sB + chunk * 1024;
  }
  const char* aRd[2][4]; const char* bRd[2][4];
  #pragma unroll
  for (int ks = 0; ks < 2; ++ks) {
    #pragma unroll
    for (int f = 0; f < 4; ++f) {
      int ra = wr * 64 + f * 16 + li;
      aRd[ks][f] = (const char*)sA + ra * 128 + ((ks * 64 + g * 16) ^ ((ra & 7) << 4));
      int rb = wc * 64 + f * 16 + li;
      bRd[ks][f] = (const char*)sB + rb * 128 + ((ks * 64 + g * 16) ^ ((rb & 7) << 4));
    }
  }

  const f32x4 fz = {0.f, 0.f, 0.f, 0.f};
  f32x4 acc[4][4];
  #pragma unroll
  for (int i = 0; i < 4; ++i)
    #pragma unroll
    for (int j = 0; j < 4; ++j) acc[i][j] = fz;

  for (int k0 = 0; k0 < K; k0 += 64) {
    #pragma unroll
    for (int j = 0; j < 4; ++j) { g2l16(aSrc[j], aDst[j]); g2l16(bSrc[j], bDst[j]); }
    #pragma unroll
    for (int j = 0; j < 4; ++j) { aSrc[j] += 128; bSrc[j] += 128; }
    __syncthreads();
    bf16x8 af[2][4], bfv[2][4];
    #pragma unroll
    for (int ks = 0; ks < 2; ++ks)
      #pragma unroll
      for (int f = 0; f < 4; ++f) { af[ks][f] = ld8(aRd[ks][f]); bfv[ks][f] = ld8(bRd[ks][f]); }
    #pragma unroll
    for (int ks = 0; ks < 2; ++ks)
      #pragma unroll
      for (int mf = 0; mf < 4; ++mf)
        #pragma unroll
        for (int nf = 0; nf < 4; ++nf)
          acc[mf][nf] = __builtin_amdgcn_mfma_f32_16x16x32_bf16(af[ks][mf], bfv[ks][nf], acc[mf][nf], 0, 0, 0);
    __syncthreads();
  }

  if (Cf) {
    #pragma unroll
    for (int mf = 0; mf < 4; ++mf)
      #pragma unroll
      for (int nf = 0; nf < 4; ++nf)
        #pragma unroll
        for (int r = 0; r < 4; ++r) {
          int gm = bm + wr * 64 + mf * 16 + g * 4 + r;
          int gn = bn + wc * 64 + nf * 16 + li;
          Cf[(size_t)gm * N + gn] = acc[mf][nf][r];
        }
  } else {
    #pragma unroll
    for (int mf = 0; mf < 4; ++mf)
      #pragma unroll
      for (int nf = 0; nf < 4; ++nf)
        #pragma unroll
        for (int r = 0; r < 4; ++r) {
          int gm = bm + wr * 64 + mf * 16 + g * 4 + r;
          int gn = bn + wc * 64 + nf * 16 + li;
          Cb[(size_t)gm * N + gn] = f2bf(acc[mf][nf][r]);
        }
  }
}

// ---------------- flash attention + fused PMSNorm (split-k, balanced) ----------------
// Unchanged from r5/r6.
__global__ __launch_bounds__(512, 2) void attn_kernel(
    const u16* __restrict__ qkv, const u16* __restrict__ Vt,
    const float* __restrict__ nw, u16* __restrict__ Mrg) {
  __shared__ __align__(16) char smem[106496];       // 104 KiB
  char* sKb = smem;
  char* sVb = smem + 65536;
  char* sPb = smem + 65536 + 32768;
  float* oex  = (float*)smem;
  float* mlex = (float*)(smem + 65536);

  const int c = blockIdx.x;
  const int bh = c & 15, iu = c >> 4;
  const int b = bh >> 3, h = bh & 7;
  const int tid = threadIdx.x, lane = tid & 63, w = tid >> 6;
  const int kh = w >> 2, wq = w & 3;
  const int g = lane >> 4, li = lane & 15;
  const float MASKV = -30000.0f;
  const float MINIT = -1000.0f;
  const float isc = 1.0f / 64.0f; // 1 / (sqrt(256) * (LAYER_IDX+1))
  const f32x4 fz = {0.f, 0.f, 0.f, 0.f};
  const size_t KADV = (size_t)32 * 6144 * 2;

  #pragma unroll 1
  for (int uu = 0; uu < 2; ++uu) {
    const int qt = uu ? (31 - iu) : iu;
    const int nt = qt + 1;
    const int kvb0 = kh * nt * 32;

    int qrow = qt * 64 + wq * 16 + li;
    const u16* qp = qkv + (size_t)(b * 2048 + qrow) * 6144 + h * 256;
    bf16x8 qf[8];
    #pragma unroll
    for (int c8 = 0; c8 < 8; ++c8) qf[c8] = ld8(qp + c8 * 32 + g * 8);

    const char* kSrc[4]; u32 kDoff[4];
    #pragma unroll
    for (int j = 0; j < 4; ++j) {
      int chunk = wq * 4 + j;
      int o = chunk * 1024 + lane * 16;
      int row = o >> 9, cb = o & 511;
      int cbs = cb ^ ((row & 7) << 4);
      kSrc[j] = (const char*)qkv + ((size_t)(b * 2048 + kvb0 + row) * 6144 + 2048 + h * 256) * 2 + cbs;
      kDoff[j] = chunk * 1024;
    }
    const char* vSrc[4]; char* vDst[4];
    #pragma unroll
    for (int j = 0; j < 4; ++j) {
      int chunk = wq * 4 + j;
      int o = chunk * 1024 + lane * 16;
      int row = o >> 6, cb = o & 63;
      int cbs = cb ^ (((row >> 1) & 3) << 4);
      vSrc[j] = (const char*)Vt + ((size_t)(bh * 256 + row) * 2048 + kvb0) * 2 + cbs;
      vDst[j] = sVb + kh * 16384 + chunk * 1024;
    }

    f32x4 o_[16];
    #pragma unroll
    for (int nf = 0; nf < 16; ++nf) o_[nf] = fz;
    float m_[4] = {MINIT, MINIT, MINIT, MINIT};
    float l_[4] = {0.f, 0.f, 0.f, 0.f};

    {
      char* kb0 = sKb + (kh * 2 + 0) * 16384;
      #pragma unroll
      for (int j = 0; j < 4; ++j) { g2l16(kSrc[j], kb0 + kDoff[j]); kSrc[j] += KADV; }
    }
    asm volatile("s_waitcnt vmcnt(0)" ::: "memory");
    asm volatile("s_barrier" ::: "memory");

    int cur = 0;
    for (int t = 0; t < nt; ++t) {
      const bool more = (t < nt - 1);
      #pragma unroll
      for (int j = 0; j < 4; ++j) { g2l16(vSrc[j], vDst[j]); vSrc[j] += 64; }
      if (more) {
        char* kb = sKb + (kh * 2 + (cur ^ 1)) * 16384;
        #pragma unroll
        for (int j = 0; j < 4; ++j) { g2l16(kSrc[j], kb + kDoff[j]); kSrc[j] += KADV; }
      }

      f32x4 sacc[2];
      const char* kbase = sKb + (kh * 2 + cur) * 16384;
      __builtin_amdgcn_s_setprio(1);
      #pragma unroll
      for (int nf = 0; nf < 2; ++nf) {
        int row = nf * 16 + li;
        int swz = (row & 7) << 4;
        const char* kr = kbase + row * 512;
        f32x4 sa = fz, sb = fz;
        #pragma unroll
        for (int c8 = 0; c8 < 4; ++c8) {
          sa = __builtin_amdgcn_mfma_f32_16x16x32_bf16(qf[c8],     ld8(kr + ((c8 * 64 + g * 16) ^ swz)),       sa, 0, 0, 0);
          sb = __builtin_amdgcn_mfma_f32_16x16x32_bf16(qf[c8 + 4], ld8(kr + (((c8 + 4) * 64 + g * 16) ^ swz)), sb, 0, 0, 0);
        }
        sacc[nf] = sa + sb;
      }
      __builtin_amdgcn_s_setprio(0);

      const int tidx = kh * nt + t;
      const bool diag = (tidx >= 2 * qt);
      float p[2][4], m0[4];
      #pragma unroll
      for (int r = 0; r < 4; ++r) {
        int qr = qt * 64 + wq * 16 + g * 4 + r;
        float a0 = sacc[0][r] * isc;
        float a1 = sacc[1][r] * isc;
        if (diag) {
          if (tidx * 32 + li > qr) a0 = MASKV;
          if (tidx * 32 + 16 + li > qr) a1 = MASKV;
        }
        p[0][r] = a0; p[1][r] = a1;
        m0[r] = fmaxf(a0, a1);
      }
      bool need = (m0[0] > m_[0] + 8.f) || (m0[1] > m_[1] + 8.f) ||
                  (m0[2] > m_[2] + 8.f) || (m0[3] > m_[3] + 8.f);
      if (__any(need)) {
        #pragma unroll
        for (int r = 0; r < 4; ++r) {
          float mx = m0[r];
          mx = fmaxf(mx, __shfl_xor(mx, 1));
          mx = fmaxf(mx, __shfl_xor(mx, 2));
          mx = fmaxf(mx, __shfl_xor(mx, 4));
          mx = fmaxf(mx, __shfl_xor(mx, 8));
          float mn = fmaxf(m_[r], mx);
          float sc = __expf(m_[r] - mn);
          l_[r] *= sc; m_[r] = mn;
          #pragma unroll
          for (int nf = 0; nf < 16; ++nf) o_[nf][r] *= sc;
        }
      }
      #pragma unroll
      for (int r = 0; r < 4; ++r) {
        float e0 = __expf(p[0][r] - m_[r]);
        float e1 = __expf(p[1][r] - m_[r]);
        p[0][r] = e0; p[1][r] = e1;
        l_[r] += e0 + e1;
      }

      if (more) asm volatile("s_waitcnt vmcnt(4)" ::: "memory");
      else      asm volatile("s_waitcnt vmcnt(0)" ::: "memory");
      asm volatile("s_barrier" ::: "memory");

      char* sPw = sPb + kh * 4096 + wq * 1024;
      #pragma unroll
      for (int r = 0; r < 4; ++r) {
        int row = g * 4 + r;
        int swz = ((row >> 1) & 3) << 4;
        #pragma unroll
        for (int nf = 0; nf < 2; ++nf)
          *(u16*)(sPw + row * 64 + (((nf * 16 + li) * 2) ^ swz)) = f2bf(p[nf][r]);
      }
      asm volatile("s_waitcnt lgkmcnt(0)" ::: "memory");
      __builtin_amdgcn_sched_barrier(0);

      __builtin_amdgcn_s_setprio(1);
      {
        const char* vb = sVb + kh * 16384;
        bf16x8 pa = ld8(sPw + li * 64 + ((g * 16) ^ (((li >> 1) & 3) << 4)));
        #pragma unroll
        for (int nf = 0; nf < 16; ++nf) {
          int row = nf * 16 + li;
          bf16x8 vf = ld8(vb + row * 64 + ((g * 16) ^ (((row >> 1) & 3) << 4)));
          o_[nf] = __builtin_amdgcn_mfma_f32_16x16x32_bf16(pa, vf, o_[nf], 0, 0, 0);
        }
      }
      __builtin_amdgcn_s_setprio(0);

      asm volatile("s_barrier" ::: "memory");
      if (more) asm volatile("s_waitcnt vmcnt(0)" ::: "memory");
      cur ^= 1;
    }

    if (kh == 1) {
      #pragma unroll
      for (int nf = 0; nf < 16; ++nf)
        *(f32x4*)(oex + wq * 4096 + nf * 256 + lane * 4) = o_[nf];
      #pragma unroll
      for (int r = 0; r < 4; ++r) {
        mlex[wq * 512 + r * 64 + lane] = l_[r];
        mlex[wq * 512 + 256 + r * 64 + lane] = m_[r];
      }
    }
    __syncthreads();
    if (kh == 0) {
      float aw[4], bw[4], inv_l[4];
      #pragma unroll
      for (int r = 0; r < 4; ++r) {
        float mB = mlex[wq * 512 + 256 + r * 64 + lane];
        float lB = mlex[wq * 512 + r * 64 + lane];
        float mm = fmaxf(m_[r], mB);
        aw[r] = __expf(m_[r] - mm);
        bw[r] = __expf(mB - mm);
        float lr = l_[r] * aw[r] + lB * bw[r];
        lr += __shfl_xor(lr, 1);
        lr += __shfl_xor(lr, 2);
        lr += __shfl_xor(lr, 4);
        lr += __shfl_xor(lr, 8);
        inv_l[r] = 1.0f / lr;
      }
      #pragma unroll
      for (int nf = 0; nf < 16; ++nf) {
        f32x4 ob = *(f32x4*)(oex + wq * 4096 + nf * 256 + lane * 4);
        #pragma unroll
        for (int r = 0; r < 4; ++r)
          o_[nf][r] = o_[nf][r] * aw[r] + ob[r] * bw[r];
      }
      #pragma unroll
      for (int r = 0; r < 4; ++r) {
        float ss = 0.f;
        #pragma unroll
        for (int nf = 0; nf < 16; ++nf) {
          float v = o_[nf][r] * inv_l[r];
          ss += v * v;
        }
        ss += __shfl_xor(ss, 1);
        ss += __shfl_xor(ss, 2);
        ss += __shfl_xor(ss, 4);
        ss += __shfl_xor(ss, 8);
        float rms = rsqrtf(ss * (1.0f / 256.0f) + 1e-5f);
        int row = qt * 64 + wq * 16 + g * 4 + r;
        #pragma unroll
        for (int nf = 0; nf < 16; ++nf) {
          int d = nf * 16 + li;
          float v = o_[nf][r] * inv_l[r] * rms * nw[d];
          Mrg[((size_t)(b * 2048 + row)) * 2048 + h * 256 + d] = f2bf(v);
        }
      }
    }
    __syncthreads();
  }
}

extern "C" void kernel_launch(void* const* d_in, const int* in_sizes, int n_in,
                              void* d_out, int out_size, void* d_ws, size_t ws_size,
                              hipStream_t stream) {
  const float* hs  = (const float*)d_in[0];   // [2,2048,2048]
  const float* wat = (const float*)d_in[1];   // [2048,6144]
  const float* wpr = (const float*)d_in[2];   // [2048,2048]
  const float* nw  = (const float*)d_in[3];   // [256]
  float* out = (float*)d_out;                 // [2,2048,2048] f32

  char* ws = (char*)d_ws;
  u16* Xb   = (u16*)(ws + 0);                    // 16 MiB  [4096][2048] bf16
  u16* Wp_t = (u16*)(ws + (16u << 20));          //  8 MiB  [2048][2048] bf16 (w_proj^T)
  u16* Qkv  = (u16*)(ws + (24u << 20));          // 48 MiB  [4096][6144] bf16
  u16* Vt   = (u16*)(ws + (72u << 20));          // 16 MiB  [16][256][2048] bf16
  u16* Mrg  = Xb;                                // aliases Xb (dead after GEMM1)
  u16* Wa_t = (u16*)d_out;                       // 24 MiB scratch (w_attn^T [6144][2048])

  dim3 t328(32, 8);
  cast_bf16_kernel<<<4096, 256, 0, stream>>>(hs, Xb, 1048576);
  tcast_kernel<<<dim3(192, 64), t328, 0, stream>>>(wat, Wa_t, 2048, 6144);
  tcast_kernel<<<dim3(64, 64), t328, 0, stream>>>(wpr, Wp_t, 2048, 2048);
  gemm256_kernel<<<dim3(32, 16), 512, 0, stream>>>(Xb, Wa_t, Qkv, 4096, 6144, 2048);
  tv_kernel<<<dim3(8, 64, 16), t328, 0, stream>>>(Qkv, Vt);
  attn_kernel<<<256, 512, 0, stream>>>(Qkv, Vt, nw, Mrg);
  gemm_bt_kernel<<<dim3(16, 32), 256, 0, stream>>>(Mrg, Wp_t, out, nullptr, 4096, 2048, 2048);
  (void)in_sizes; (void)n_in; (void)out_size; (void)ws_size;
}

// Round 8
// 247.689 us; speedup vs baseline: 1.1249x; 1.0156x over previous
//
#include <hip/hip_runtime.h>
#include <math.h>

// PGTAttention fused block, MI355X gfx950. Round 8.
// Change vs r7: both GEMMs moved to an 8-phase fine-interleaved schedule (T2+T3+T4+T5):
// K-split LDS halves ([buf][khalf][rows][32]), per-phase {ds_read -> stage -> barrier ->
// lgkm0 -> MFMA -> barrier}, counted vmcnt W1=4+BSTG / W2=2 derived instruction-exact
// (never drained mid-loop). qkv 256x192 (grid 512 = 2 exact rounds), proj 256x128
// (grid 256 = 1 exact round). Attention / preps frozen from r5-r7.

typedef unsigned short u16;
typedef unsigned int   u32;
typedef u16   u16x8 __attribute__((ext_vector_type(8)));
typedef __bf16 bf16x8 __attribute__((ext_vector_type(8)));
typedef float f32x4 __attribute__((ext_vector_type(4)));

#define GPTR(p) ((const __attribute__((address_space(1))) void*)(p))
#define LPTR(p) ((__attribute__((address_space(3))) void*)(p))

__device__ __forceinline__ u16 f2bf(float x) {
  u32 u = __float_as_uint(x);
  return (u16)((u + 0x7fffu + ((u >> 16) & 1u)) >> 16);  // RNE
}

__device__ __forceinline__ bf16x8 ld8(const void* p) {
  u16x8 v = *reinterpret_cast<const u16x8*>(p);
  return __builtin_bit_cast(bf16x8, v);
}

// global->LDS direct copy, 16B/lane; LDS dest = wave-uniform base + lane*16.
__device__ __forceinline__ void g2l16(const void* g, void* l) {
  __builtin_amdgcn_global_load_lds(GPTR(g), LPTR(l), 16, 0, 0);
}

// ---------------- elementwise cast f32 -> bf16, 8 elems/thread ----------------
__global__ void cast_bf16_kernel(const float* __restrict__ in, u16* __restrict__ out, int n8) {
  int i = blockIdx.x * 256 + threadIdx.x;
  if (i >= n8) return;
  const float4* p = reinterpret_cast<const float4*>(in) + (size_t)i * 2;
  float4 a = p[0], b = p[1];
  u16x8 v;
  v[0] = f2bf(a.x); v[1] = f2bf(a.y); v[2] = f2bf(a.z); v[3] = f2bf(a.w);
  v[4] = f2bf(b.x); v[5] = f2bf(b.y); v[6] = f2bf(b.z); v[7] = f2bf(b.w);
  reinterpret_cast<u16x8*>(out)[i] = v;
}

// ---------------- transpose + cast: out[c][r] = bf16(in[r][c]), in is R x C f32 -------
__global__ void tcast_kernel(const float* __restrict__ in, u16* __restrict__ out, int R, int C) {
  __shared__ float t[32][33];
  int bx = blockIdx.x * 32, by = blockIdx.y * 32;
  int x = threadIdx.x, y = threadIdx.y;  // (32, 8)
  #pragma unroll
  for (int k = 0; k < 32; k += 8)
    t[y + k][x] = in[(size_t)(by + y + k) * C + (bx + x)];
  __syncthreads();
  #pragma unroll
  for (int k = 0; k < 32; k += 8)
    out[(size_t)(bx + y + k) * R + (by + x)] = f2bf(t[x][y + k]);
}

// ------- V transpose from qkv: out[bh][d][s] = qkv[b][s][4096 + h*256 + d] ----------
__global__ void tv_kernel(const u16* __restrict__ qkv, u16* __restrict__ out) {
  __shared__ u16 t[32][33];
  int bh = blockIdx.z, b = bh >> 3, h = bh & 7;
  const u16* ip = qkv + (size_t)b * 2048 * 6144 + 4096 + h * 256;
  u16* op = out + (size_t)bh * 256 * 2048;
  int bx = blockIdx.x * 32, by = blockIdx.y * 32;  // bx: d, by: s
  int x = threadIdx.x, y = threadIdx.y;
  #pragma unroll
  for (int k = 0; k < 32; k += 8)
    t[y + k][x] = ip[(size_t)(by + y + k) * 6144 + (bx + x)];
  __syncthreads();
  #pragma unroll
  for (int k = 0; k < 32; k += 8)
    op[(size_t)(bx + y + k) * 2048 + (by + x)] = t[x][y + k];
}

// ---------------- 8-phase deep-pipelined GEMM: C = A[M,K] * Bt[N,K]^T ----------------
// 512 thr (8 waves, WM x WN), BM = WM*MF*16, BN = WN*NF*16, BK = 64 (2 k-halves).
// LDS: A [buf][khalf][256][32] (16KB halves), B [buf][khalf][BN][32]. Rows 64B,
// swizzle ((row>>1)&3)<<4 on stage-source AND read (involution; residual 2-way = free).
// Phases per tile k (cbuf=k&1): p0: read (klo,mf-half0)+B-klo, stage A-khi(k+1)+B(k+1)
// -> nbuf; p1: read (klo,half1), W1 vmcnt(4+BSTG); p2: read (khi,half0)+B-khi, stage
// A-klo(k+2) -> cbuf (region freed at p1's barrier); p3: read (khi,half1), W2 vmcnt(2).
// Each phase: [ds_read; stage; s_barrier; lgkmcnt(0); setprio(1) MFMA setprio(0); s_barrier].
template<int WM, int WN, int MF, int NF, bool F32OUT>
__global__ __launch_bounds__(512, 2) void gemm8p_kernel(
    const u16* __restrict__ A, const u16* __restrict__ Bt,
    float* __restrict__ Cf, u16* __restrict__ Cb, int M, int N, int K) {
  constexpr int BM = WM * MF * 16;
  constexpr int BN = WN * NF * 16;
  constexpr int BSTG = (BN * 128) / 8192;   // B stage instructions per tile (per thread)
  constexpr int BBYTES = BN * 128;          // per-buf B bytes (both k-halves)
  __shared__ __align__(16) char smem[65536 + 2 * BBYTES];
  char* sAb = smem;           // (buf*2 + khalf)*16384 + row*64 + col
  char* sBb = smem + 65536;   // buf*BBYTES + khalf*(BN*64) + row*64 + col

  const int tid = threadIdx.x, lane = tid & 63, w = tid >> 6;
  const int wr = w / WN, wc = w % WN;
  const int g = lane >> 4, li = lane & 15;
  const int bn = blockIdx.x * BN, bm = blockIdx.y * BM;

  // staging sources (per-thread, pre-inverse-swizzled); advance 128B per K-tile
  const char* aS[2][2];  // [khalf][instr]
  #pragma unroll
  for (int h = 0; h < 2; ++h)
    #pragma unroll
    for (int j = 0; j < 2; ++j) {
      int o = j * 8192 + tid * 16;
      int row = o >> 6;
      int col = (o & 63) ^ (((row >> 1) & 3) << 4);
      aS[h][j] = (const char*)A + (size_t)(bm + row) * K * 2 + h * 64 + col;
    }
  const char* bS[BSTG];
  #pragma unroll
  for (int j = 0; j < BSTG; ++j) {
    int o = j * 8192 + tid * 16;
    int h = o / (BN * 64);
    int rem = o - h * (BN * 64);
    int row = rem >> 6;
    int col = (rem & 63) ^ (((row >> 1) & 3) << 4);
    bS[j] = (const char*)Bt + (size_t)(bn + row) * K * 2 + h * 64 + col;
  }

  // ds_read offsets (within a khalf region)
  u32 aRd[MF], bRd[NF];
  #pragma unroll
  for (int mf = 0; mf < MF; ++mf) {
    int row = wr * (MF * 16) + mf * 16 + li;
    aRd[mf] = row * 64 + ((g * 16) ^ (((row >> 1) & 3) << 4));
  }
  #pragma unroll
  for (int nf = 0; nf < NF; ++nf) {
    int row = wc * (NF * 16) + nf * 16 + li;
    bRd[nf] = row * 64 + ((g * 16) ^ (((row >> 1) & 3) << 4));
  }

  auto stageA = [&](int h, int buf) {  // 2 instructions
    char* d = sAb + (buf * 2 + h) * 16384 + w * 1024;
    g2l16(aS[h][0], d);
    g2l16(aS[h][1], d + 8192);
    aS[h][0] += 128; aS[h][1] += 128;
  };
  auto stageB = [&](int buf) {  // BSTG instructions
    char* d = sBb + buf * BBYTES + w * 1024;
    #pragma unroll
    for (int j = 0; j < BSTG; ++j) { g2l16(bS[j], d + j * 8192); bS[j] += 128; }
  };

  const f32x4 fz = {0.f, 0.f, 0.f, 0.f};
  f32x4 acc[MF][NF];
  #pragma unroll
  for (int i = 0; i < MF; ++i)
    #pragma unroll
    for (int j = 0; j < NF; ++j) acc[i][j] = fz;

  const int NT = K >> 6;

  // prologue: A-klo(0), B(0), A-khi(0), A-klo(1); tile-0 k-lo data landed
  stageA(0, 0);
  stageB(0);
  stageA(1, 0);
  stageA(0, 1);
  asm volatile("s_waitcnt vmcnt(4)" ::: "memory");
  asm volatile("s_barrier" ::: "memory");

  for (int k = 0; k < NT; ++k) {
    const int cbuf = k & 1, nbuf = cbuf ^ 1;
    const bool s1 = (k + 1 < NT), s2 = (k + 2 < NT);
    const char* sAc = sAb + cbuf * 32768;
    const char* sBc = sBb + cbuf * BBYTES;
    bf16x8 aR[MF / 2], bR[NF];

    // ---- phase 0: ks=0, mf-half 0 (+ B-klo hoist) ----
    #pragma unroll
    for (int i = 0; i < MF / 2; ++i) aR[i] = ld8(sAc + aRd[i]);
    #pragma unroll
    for (int nf = 0; nf < NF; ++nf) bR[nf] = ld8(sBc + bRd[nf]);
    if (s1) { stageA(1, nbuf); stageB(nbuf); }
    asm volatile("s_barrier" ::: "memory");
    asm volatile("s_waitcnt lgkmcnt(0)" ::: "memory");
    __builtin_amdgcn_sched_barrier(0);
    __builtin_amdgcn_s_setprio(1);
    #pragma unroll
    for (int i = 0; i < MF / 2; ++i)
      #pragma unroll
      for (int nf = 0; nf < NF; ++nf)
        acc[i][nf] = __builtin_amdgcn_mfma_f32_16x16x32_bf16(aR[i], bR[nf], acc[i][nf], 0, 0, 0);
    __builtin_amdgcn_s_setprio(0);
    asm volatile("s_barrier" ::: "memory");

    // ---- phase 1: ks=0, mf-half 1 ----
    #pragma unroll
    for (int i = 0; i < MF / 2; ++i) aR[i] = ld8(sAc + aRd[MF / 2 + i]);
    asm volatile("s_barrier" ::: "memory");
    asm volatile("s_waitcnt lgkmcnt(0)" ::: "memory");
    __builtin_amdgcn_sched_barrier(0);
    __builtin_amdgcn_s_setprio(1);
    #pragma unroll
    for (int i = 0; i < MF / 2; ++i)
      #pragma unroll
      for (int nf = 0; nf < NF; ++nf)
        acc[MF / 2 + i][nf] = __builtin_amdgcn_mfma_f32_16x16x32_bf16(aR[i], bR[nf], acc[MF / 2 + i][nf], 0, 0, 0);
    __builtin_amdgcn_s_setprio(0);
    // W1: A-khi(k)/B(k) landed (leaves the 4+BSTG tile-(k+1) stages in flight)
    if (s1) asm volatile("s_waitcnt vmcnt(%0)" :: "i"(4 + BSTG) : "memory");
    else    asm volatile("s_waitcnt vmcnt(0)" ::: "memory");
    asm volatile("s_barrier" ::: "memory");

    // ---- phase 2: ks=1, mf-half 0 (+ B-khi hoist; stage A-klo(k+2) into freed region) --
    #pragma unroll
    for (int i = 0; i < MF / 2; ++i) aR[i] = ld8(sAc + 16384 + aRd[i]);
    #pragma unroll
    for (int nf = 0; nf < NF; ++nf) bR[nf] = ld8(sBc + BN * 64 + bRd[nf]);
    if (s2) stageA(0, cbuf);
    asm volatile("s_barrier" ::: "memory");
    asm volatile("s_waitcnt lgkmcnt(0)" ::: "memory");
    __builtin_amdgcn_sched_barrier(0);
    __builtin_amdgcn_s_setprio(1);
    #pragma unroll
    for (int i = 0; i < MF / 2; ++i)
      #pragma unroll
      for (int nf = 0; nf < NF; ++nf)
        acc[i][nf] = __builtin_amdgcn_mfma_f32_16x16x32_bf16(aR[i], bR[nf], acc[i][nf], 0, 0, 0);
    __builtin_amdgcn_s_setprio(0);
    asm volatile("s_barrier" ::: "memory");

    // ---- phase 3: ks=1, mf-half 1 ----
    #pragma unroll
    for (int i = 0; i < MF / 2; ++i) aR[i] = ld8(sAc + 16384 + aRd[MF / 2 + i]);
    asm volatile("s_barrier" ::: "memory");
    asm volatile("s_waitcnt lgkmcnt(0)" ::: "memory");
    __builtin_amdgcn_sched_barrier(0);
    __builtin_amdgcn_s_setprio(1);
    #pragma unroll
    for (int i = 0; i < MF / 2; ++i)
      #pragma unroll
      for (int nf = 0; nf < NF; ++nf)
        acc[MF / 2 + i][nf] = __builtin_amdgcn_mfma_f32_16x16x32_bf16(aR[i], bR[nf], acc[MF / 2 + i][nf], 0, 0, 0);
    __builtin_amdgcn_s_setprio(0);
    // W2: tile-(k+1) fully landed (leaves only the 2 A-klo(k+2) stages in flight)
    if (s2) asm volatile("s_waitcnt vmcnt(2)" ::: "memory");
    else    asm volatile("s_waitcnt vmcnt(0)" ::: "memory");
    asm volatile("s_barrier" ::: "memory");
  }

  #pragma unroll
  for (int mf = 0; mf < MF; ++mf)
    #pragma unroll
    for (int nf = 0; nf < NF; ++nf)
      #pragma unroll
      for (int r = 0; r < 4; ++r) {
        int gm = bm + wr * (MF * 16) + mf * 16 + g * 4 + r;
        int gn = bn + wc * (NF * 16) + nf * 16 + li;
        if (F32OUT) Cf[(size_t)gm * N + gn] = acc[mf][nf][r];
        else        Cb[(size_t)gm * N + gn] = f2bf(acc[mf][nf][r]);
      }
}

// ---------------- flash attention + fused PMSNorm (split-k, balanced) ----------------
// Unchanged from r5-r7.
__global__ __launch_bounds__(512, 2) void attn_kernel(
    const u16* __restrict__ qkv, const u16* __restrict__ Vt,
    const float* __restrict__ nw, u16* __restrict__ Mrg) {
  __shared__ __align__(16) char smem[106496];       // 104 KiB
  char* sKb = smem;
  char* sVb = smem + 65536;
  char* sPb = smem + 65536 + 32768;
  float* oex  = (float*)smem;
  float* mlex = (float*)(smem + 65536);

  const int c = blockIdx.x;
  const int bh = c & 15, iu = c >> 4;
  const int b = bh >> 3, h = bh & 7;
  const int tid = threadIdx.x, lane = tid & 63, w = tid >> 6;
  const int kh = w >> 2, wq = w & 3;
  const int g = lane >> 4, li = lane & 15;
  const float MASKV = -30000.0f;
  const float MINIT = -1000.0f;
  const float isc = 1.0f / 64.0f; // 1 / (sqrt(256) * (LAYER_IDX+1))
  const f32x4 fz = {0.f, 0.f, 0.f, 0.f};
  const size_t KADV = (size_t)32 * 6144 * 2;

  #pragma unroll 1
  for (int uu = 0; uu < 2; ++uu) {
    const int qt = uu ? (31 - iu) : iu;
    const int nt = qt + 1;
    const int kvb0 = kh * nt * 32;

    int qrow = qt * 64 + wq * 16 + li;
    const u16* qp = qkv + (size_t)(b * 2048 + qrow) * 6144 + h * 256;
    bf16x8 qf[8];
    #pragma unroll
    for (int c8 = 0; c8 < 8; ++c8) qf[c8] = ld8(qp + c8 * 32 + g * 8);

    const char* kSrc[4]; u32 kDoff[4];
    #pragma unroll
    for (int j = 0; j < 4; ++j) {
      int chunk = wq * 4 + j;
      int o = chunk * 1024 + lane * 16;
      int row = o >> 9, cb = o & 511;
      int cbs = cb ^ ((row & 7) << 4);
      kSrc[j] = (const char*)qkv + ((size_t)(b * 2048 + kvb0 + row) * 6144 + 2048 + h * 256) * 2 + cbs;
      kDoff[j] = chunk * 1024;
    }
    const char* vSrc[4]; char* vDst[4];
    #pragma unroll
    for (int j = 0; j < 4; ++j) {
      int chunk = wq * 4 + j;
      int o = chunk * 1024 + lane * 16;
      int row = o >> 6, cb = o & 63;
      int cbs = cb ^ (((row >> 1) & 3) << 4);
      vSrc[j] = (const char*)Vt + ((size_t)(bh * 256 + row) * 2048 + kvb0) * 2 + cbs;
      vDst[j] = sVb + kh * 16384 + chunk * 1024;
    }

    f32x4 o_[16];
    #pragma unroll
    for (int nf = 0; nf < 16; ++nf) o_[nf] = fz;
    float m_[4] = {MINIT, MINIT, MINIT, MINIT};
    float l_[4] = {0.f, 0.f, 0.f, 0.f};

    {
      char* kb0 = sKb + (kh * 2 + 0) * 16384;
      #pragma unroll
      for (int j = 0; j < 4; ++j) { g2l16(kSrc[j], kb0 + kDoff[j]); kSrc[j] += KADV; }
    }
    asm volatile("s_waitcnt vmcnt(0)" ::: "memory");
    asm volatile("s_barrier" ::: "memory");

    int cur = 0;
    for (int t = 0; t < nt; ++t) {
      const bool more = (t < nt - 1);
      #pragma unroll
      for (int j = 0; j < 4; ++j) { g2l16(vSrc[j], vDst[j]); vSrc[j] += 64; }
      if (more) {
        char* kb = sKb + (kh * 2 + (cur ^ 1)) * 16384;
        #pragma unroll
        for (int j = 0; j < 4; ++j) { g2l16(kSrc[j], kb + kDoff[j]); kSrc[j] += KADV; }
      }

      f32x4 sacc[2];
      const char* kbase = sKb + (kh * 2 + cur) * 16384;
      __builtin_amdgcn_s_setprio(1);
      #pragma unroll
      for (int nf = 0; nf < 2; ++nf) {
        int row = nf * 16 + li;
        int swz = (row & 7) << 4;
        const char* kr = kbase + row * 512;
        f32x4 sa = fz, sb = fz;
        #pragma unroll
        for (int c8 = 0; c8 < 4; ++c8) {
          sa = __builtin_amdgcn_mfma_f32_16x16x32_bf16(qf[c8],     ld8(kr + ((c8 * 64 + g * 16) ^ swz)),       sa, 0, 0, 0);
          sb = __builtin_amdgcn_mfma_f32_16x16x32_bf16(qf[c8 + 4], ld8(kr + (((c8 + 4) * 64 + g * 16) ^ swz)), sb, 0, 0, 0);
        }
        sacc[nf] = sa + sb;
      }
      __builtin_amdgcn_s_setprio(0);

      const int tidx = kh * nt + t;
      const bool diag = (tidx >= 2 * qt);
      float p[2][4], m0[4];
      #pragma unroll
      for (int r = 0; r < 4; ++r) {
        int qr = qt * 64 + wq * 16 + g * 4 + r;
        float a0 = sacc[0][r] * isc;
        float a1 = sacc[1][r] * isc;
        if (diag) {
          if (tidx * 32 + li > qr) a0 = MASKV;
          if (tidx * 32 + 16 + li > qr) a1 = MASKV;
        }
        p[0][r] = a0; p[1][r] = a1;
        m0[r] = fmaxf(a0, a1);
      }
      bool need = (m0[0] > m_[0] + 8.f) || (m0[1] > m_[1] + 8.f) ||
                  (m0[2] > m_[2] + 8.f) || (m0[3] > m_[3] + 8.f);
      if (__any(need)) {
        #pragma unroll
        for (int r = 0; r < 4; ++r) {
          float mx = m0[r];
          mx = fmaxf(mx, __shfl_xor(mx, 1));
          mx = fmaxf(mx, __shfl_xor(mx, 2));
          mx = fmaxf(mx, __shfl_xor(mx, 4));
          mx = fmaxf(mx, __shfl_xor(mx, 8));
          float mn = fmaxf(m_[r], mx);
          float sc = __expf(m_[r] - mn);
          l_[r] *= sc; m_[r] = mn;
          #pragma unroll
          for (int nf = 0; nf < 16; ++nf) o_[nf][r] *= sc;
        }
      }
      #pragma unroll
      for (int r = 0; r < 4; ++r) {
        float e0 = __expf(p[0][r] - m_[r]);
        float e1 = __expf(p[1][r] - m_[r]);
        p[0][r] = e0; p[1][r] = e1;
        l_[r] += e0 + e1;
      }

      if (more) asm volatile("s_waitcnt vmcnt(4)" ::: "memory");
      else      asm volatile("s_waitcnt vmcnt(0)" ::: "memory");
      asm volatile("s_barrier" ::: "memory");

      char* sPw = sPb + kh * 4096 + wq * 1024;
      #pragma unroll
      for (int r = 0; r < 4; ++r) {
        int row = g * 4 + r;
        int swz = ((row >> 1) & 3) << 4;
        #pragma unroll
        for (int nf = 0; nf < 2; ++nf)
          *(u16*)(sPw + row * 64 + (((nf * 16 + li) * 2) ^ swz)) = f2bf(p[nf][r]);
      }
      asm volatile("s_waitcnt lgkmcnt(0)" ::: "memory");
      __builtin_amdgcn_sched_barrier(0);

      __builtin_amdgcn_s_setprio(1);
      {
        const char* vb = sVb + kh * 16384;
        bf16x8 pa = ld8(sPw + li * 64 + ((g * 16) ^ (((li >> 1) & 3) << 4)));
        #pragma unroll
        for (int nf = 0; nf < 16; ++nf) {
          int row = nf * 16 + li;
          bf16x8 vf = ld8(vb + row * 64 + ((g * 16) ^ (((row >> 1) & 3) << 4)));
          o_[nf] = __builtin_amdgcn_mfma_f32_16x16x32_bf16(pa, vf, o_[nf], 0, 0, 0);
        }
      }
      __builtin_amdgcn_s_setprio(0);

      asm volatile("s_barrier" ::: "memory");
      if (more) asm volatile("s_waitcnt vmcnt(0)" ::: "memory");
      cur ^= 1;
    }

    if (kh == 1) {
      #pragma unroll
      for (int nf = 0; nf < 16; ++nf)
        *(f32x4*)(oex + wq * 4096 + nf * 256 + lane * 4) = o_[nf];
      #pragma unroll
      for (int r = 0; r < 4; ++r) {
        mlex[wq * 512 + r * 64 + lane] = l_[r];
        mlex[wq * 512 + 256 + r * 64 + lane] = m_[r];
      }
    }
    __syncthreads();
    if (kh == 0) {
      float aw[4], bw[4], inv_l[4];
      #pragma unroll
      for (int r = 0; r < 4; ++r) {
        float mB = mlex[wq * 512 + 256 + r * 64 + lane];
        float lB = mlex[wq * 512 + r * 64 + lane];
        float mm = fmaxf(m_[r], mB);
        aw[r] = __expf(m_[r] - mm);
        bw[r] = __expf(mB - mm);
        float lr = l_[r] * aw[r] + lB * bw[r];
        lr += __shfl_xor(lr, 1);
        lr += __shfl_xor(lr, 2);
        lr += __shfl_xor(lr, 4);
        lr += __shfl_xor(lr, 8);
        inv_l[r] = 1.0f / lr;
      }
      #pragma unroll
      for (int nf = 0; nf < 16; ++nf) {
        f32x4 ob = *(f32x4*)(oex + wq * 4096 + nf * 256 + lane * 4);
        #pragma unroll
        for (int r = 0; r < 4; ++r)
          o_[nf][r] = o_[nf][r] * aw[r] + ob[r] * bw[r];
      }
      #pragma unroll
      for (int r = 0; r < 4; ++r) {
        float ss = 0.f;
        #pragma unroll
        for (int nf = 0; nf < 16; ++nf) {
          float v = o_[nf][r] * inv_l[r];
          ss += v * v;
        }
        ss += __shfl_xor(ss, 1);
        ss += __shfl_xor(ss, 2);
        ss += __shfl_xor(ss, 4);
        ss += __shfl_xor(ss, 8);
        float rms = rsqrtf(ss * (1.0f / 256.0f) + 1e-5f);
        int row = qt * 64 + wq * 16 + g * 4 + r;
        #pragma unroll
        for (int nf = 0; nf < 16; ++nf) {
          int d = nf * 16 + li;
          float v = o_[nf][r] * inv_l[r] * rms * nw[d];
          Mrg[((size_t)(b * 2048 + row)) * 2048 + h * 256 + d] = f2bf(v);
        }
      }
    }
    __syncthreads();
  }
}

extern "C" void kernel_launch(void* const* d_in, const int* in_sizes, int n_in,
                              void* d_out, int out_size, void* d_ws, size_t ws_size,
                              hipStream_t stream) {
  const float* hs  = (const float*)d_in[0];   // [2,2048,2048]
  const float* wat = (const float*)d_in[1];   // [2048,6144]
  const float* wpr = (const float*)d_in[2];   // [2048,2048]
  const float* nw  = (const float*)d_in[3];   // [256]
  float* out = (float*)d_out;                 // [2,2048,2048] f32

  char* ws = (char*)d_ws;
  u16* Xb   = (u16*)(ws + 0);                    // 16 MiB  [4096][2048] bf16
  u16* Wp_t = (u16*)(ws + (16u << 20));          //  8 MiB  [2048][2048] bf16 (w_proj^T)
  u16* Qkv  = (u16*)(ws + (24u << 20));          // 48 MiB  [4096][6144] bf16
  u16* Vt   = (u16*)(ws + (72u << 20));          // 16 MiB  [16][256][2048] bf16
  u16* Mrg  = Xb;                                // aliases Xb (dead after GEMM1)
  u16* Wa_t = (u16*)d_out;                       // 24 MiB scratch (w_attn^T [6144][2048])

  dim3 t328(32, 8);
  cast_bf16_kernel<<<4096, 256, 0, stream>>>(hs, Xb, 1048576);
  tcast_kernel<<<dim3(192, 64), t328, 0, stream>>>(wat, Wa_t, 2048, 6144);
  tcast_kernel<<<dim3(64, 64), t328, 0, stream>>>(wpr, Wp_t, 2048, 2048);
  gemm8p_kernel<2, 4, 8, 3, false><<<dim3(32, 16), 512, 0, stream>>>(
      Xb, Wa_t, nullptr, Qkv, 4096, 6144, 2048);
  tv_kernel<<<dim3(8, 64, 16), t328, 0, stream>>>(Qkv, Vt);
  attn_kernel<<<256, 512, 0, stream>>>(Qkv, Vt, nw, Mrg);
  gemm8p_kernel<4, 2, 4, 4, true><<<dim3(16, 16), 512, 0, stream>>>(
      Mrg, Wp_t, out, nullptr, 4096, 2048, 2048);
  (void)in_sizes; (void)n_in; (void)out_size; (void)ws_size;
}

// Round 9
// 237.405 us; speedup vs baseline: 1.1736x; 1.0433x over previous
//
#include <hip/hip_runtime.h>
#include <math.h>

// PGTAttention fused block, MI355X gfx950. Round 9.
// Change vs r8: GEMMs re-tiled for 2 blocks/CU occupancy (the r7/r8 1-block/CU
// lockstep left the MFMA pipe idle in every read/barrier window; a co-resident
// independent block fills those stalls -- m114 mechanism). qkv 128x192 (80KB LDS,
// grid 1024 = 2 rounds at 2/CU), proj 128x128 (64KB, grid 512 = 1 round). Coarse
// counted-vmcnt schedule (r7-equal-to-r8), per-ks fragment reads for VGPR<=128,
// __launch_bounds__(512,4). Attention / preps frozen.

typedef unsigned short u16;
typedef unsigned int   u32;
typedef u16   u16x8 __attribute__((ext_vector_type(8)));
typedef __bf16 bf16x8 __attribute__((ext_vector_type(8)));
typedef float f32x4 __attribute__((ext_vector_type(4)));

#define GPTR(p) ((const __attribute__((address_space(1))) void*)(p))
#define LPTR(p) ((__attribute__((address_space(3))) void*)(p))

__device__ __forceinline__ u16 f2bf(float x) {
  u32 u = __float_as_uint(x);
  return (u16)((u + 0x7fffu + ((u >> 16) & 1u)) >> 16);  // RNE
}

__device__ __forceinline__ bf16x8 ld8(const void* p) {
  u16x8 v = *reinterpret_cast<const u16x8*>(p);
  return __builtin_bit_cast(bf16x8, v);
}

// global->LDS direct copy, 16B/lane; LDS dest = wave-uniform base + lane*16.
__device__ __forceinline__ void g2l16(const void* g, void* l) {
  __builtin_amdgcn_global_load_lds(GPTR(g), LPTR(l), 16, 0, 0);
}

// ---------------- elementwise cast f32 -> bf16, 8 elems/thread ----------------
__global__ void cast_bf16_kernel(const float* __restrict__ in, u16* __restrict__ out, int n8) {
  int i = blockIdx.x * 256 + threadIdx.x;
  if (i >= n8) return;
  const float4* p = reinterpret_cast<const float4*>(in) + (size_t)i * 2;
  float4 a = p[0], b = p[1];
  u16x8 v;
  v[0] = f2bf(a.x); v[1] = f2bf(a.y); v[2] = f2bf(a.z); v[3] = f2bf(a.w);
  v[4] = f2bf(b.x); v[5] = f2bf(b.y); v[6] = f2bf(b.z); v[7] = f2bf(b.w);
  reinterpret_cast<u16x8*>(out)[i] = v;
}

// ---------------- transpose + cast: out[c][r] = bf16(in[r][c]), in is R x C f32 -------
__global__ void tcast_kernel(const float* __restrict__ in, u16* __restrict__ out, int R, int C) {
  __shared__ float t[32][33];
  int bx = blockIdx.x * 32, by = blockIdx.y * 32;
  int x = threadIdx.x, y = threadIdx.y;  // (32, 8)
  #pragma unroll
  for (int k = 0; k < 32; k += 8)
    t[y + k][x] = in[(size_t)(by + y + k) * C + (bx + x)];
  __syncthreads();
  #pragma unroll
  for (int k = 0; k < 32; k += 8)
    out[(size_t)(bx + y + k) * R + (by + x)] = f2bf(t[x][y + k]);
}

// ------- V transpose from qkv: out[bh][d][s] = qkv[b][s][4096 + h*256 + d] ----------
__global__ void tv_kernel(const u16* __restrict__ qkv, u16* __restrict__ out) {
  __shared__ u16 t[32][33];
  int bh = blockIdx.z, b = bh >> 3, h = bh & 7;
  const u16* ip = qkv + (size_t)b * 2048 * 6144 + 4096 + h * 256;
  u16* op = out + (size_t)bh * 256 * 2048;
  int bx = blockIdx.x * 32, by = blockIdx.y * 32;  // bx: d, by: s
  int x = threadIdx.x, y = threadIdx.y;
  #pragma unroll
  for (int k = 0; k < 32; k += 8)
    t[y + k][x] = ip[(size_t)(by + y + k) * 6144 + (bx + x)];
  __syncthreads();
  #pragma unroll
  for (int k = 0; k < 32; k += 8)
    op[(size_t)(bx + y + k) * 2048 + (by + x)] = t[x][y + k];
}

// ------------- 2-blocks/CU pipelined GEMM: C = A[M,K] * Bt[N,K]^T (bf16 in) -------------
// 512 thr (8 waves, WM x WN), BM = WM*MF*16, BN = WN*NF*16, BK = 64.
// LDS 2 bufs of (BM+BN)*128 B; rows 128B, swizzle (row&7)<<4 both-sides involution.
// Schedule per K-tile t (buf t&1): s_barrier [buf (t+1)&1 free] -> stage(t+1) [NSTG
// gload_lds/thread] -> vmcnt(NSTG) [stage(t) landed, t+1 in flight] -> s_barrier ->
// per-ks {read frags, MFMA} x2. Small LDS/regs -> 2 blocks/CU: co-resident block
// fills read/barrier stall windows.
template<int WM, int WN, int MF, int NF, bool F32OUT>
__global__ __launch_bounds__(512, 4) void gemm2b_kernel(
    const u16* __restrict__ A, const u16* __restrict__ Bt,
    float* __restrict__ Cf, u16* __restrict__ Cb, int M, int N, int K) {
  constexpr int BM = WM * MF * 16;
  constexpr int BN = WN * NF * 16;
  constexpr int TILEB = (BM + BN) * 128;   // bytes per buffer (A then B regions)
  constexpr int NSTG = TILEB / 8192;       // stage instructions per thread per tile
  __shared__ __align__(16) char smem[2 * TILEB];

  const int tid = threadIdx.x, lane = tid & 63, w = tid >> 6;
  const int wr = w / WN, wc = w % WN;
  const int g = lane >> 4, li = lane & 15;
  const int bn = blockIdx.x * BN, bm = blockIdx.y * BM;

  // staging sources (per-thread, pre-inverse-swizzled); +128B per K-tile
  const char* src[NSTG]; u32 dOff[NSTG];
  #pragma unroll
  for (int j = 0; j < NSTG; ++j) {
    int o = j * 8192 + tid * 16;
    if (o < BM * 128) {
      int row = o >> 7;
      int col = (o & 127) ^ ((row & 7) << 4);
      src[j] = (const char*)A + (size_t)(bm + row) * K * 2 + col;
    } else {
      int rem = o - BM * 128;
      int row = rem >> 7;
      int col = (rem & 127) ^ ((row & 7) << 4);
      src[j] = (const char*)Bt + (size_t)(bn + row) * K * 2 + col;
    }
    dOff[j] = (u32)(o - lane * 16);  // wave-uniform dest base offset within buf
  }

  // fragment read offsets (ks selects k-half column group)
  u32 aRd[2][MF], bRd[2][NF];
  #pragma unroll
  for (int ks = 0; ks < 2; ++ks) {
    #pragma unroll
    for (int mf = 0; mf < MF; ++mf) {
      int row = wr * (MF * 16) + mf * 16 + li;
      aRd[ks][mf] = row * 128 + ((ks * 64 + g * 16) ^ ((row & 7) << 4));
    }
    #pragma unroll
    for (int nf = 0; nf < NF; ++nf) {
      int row = wc * (NF * 16) + nf * 16 + li;
      bRd[ks][nf] = BM * 128 + row * 128 + ((ks * 64 + g * 16) ^ ((row & 7) << 4));
    }
  }

  const f32x4 fz = {0.f, 0.f, 0.f, 0.f};
  f32x4 acc[MF][NF];
  #pragma unroll
  for (int i = 0; i < MF; ++i)
    #pragma unroll
    for (int j = 0; j < NF; ++j) acc[i][j] = fz;

  const int NT = K >> 6;
  // prologue: stage tile 0 into buf 0
  #pragma unroll
  for (int j = 0; j < NSTG; ++j) { g2l16(src[j], smem + dOff[j]); src[j] += 128; }

  for (int t = 0; t < NT; ++t) {
    const int cur = t & 1;
    const bool more = (t + 1 < NT);
    // barrier A: all waves finished reading buf[(t+1)&1] (iteration t-1's compute)
    asm volatile("s_barrier" ::: "memory");
    if (more) {
      char* nb = smem + (cur ^ 1) * TILEB;
      #pragma unroll
      for (int j = 0; j < NSTG; ++j) { g2l16(src[j], nb + dOff[j]); src[j] += 128; }
      asm volatile("s_waitcnt vmcnt(%0)" :: "i"(NSTG) : "memory");  // tile t landed
    } else {
      asm volatile("s_waitcnt vmcnt(0)" ::: "memory");
    }
    asm volatile("s_barrier" ::: "memory");  // barrier B: all staged slices visible

    const char* sb = smem + cur * TILEB;
    #pragma unroll
    for (int ks = 0; ks < 2; ++ks) {
      bf16x8 aR[MF], bR[NF];
      #pragma unroll
      for (int mf = 0; mf < MF; ++mf) aR[mf] = ld8(sb + aRd[ks][mf]);
      #pragma unroll
      for (int nf = 0; nf < NF; ++nf) bR[nf] = ld8(sb + bRd[ks][nf]);
      __builtin_amdgcn_s_setprio(1);
      #pragma unroll
      for (int mf = 0; mf < MF; ++mf)
        #pragma unroll
        for (int nf = 0; nf < NF; ++nf)
          acc[mf][nf] = __builtin_amdgcn_mfma_f32_16x16x32_bf16(aR[mf], bR[nf], acc[mf][nf], 0, 0, 0);
      __builtin_amdgcn_s_setprio(0);
    }
  }

  #pragma unroll
  for (int mf = 0; mf < MF; ++mf)
    #pragma unroll
    for (int nf = 0; nf < NF; ++nf)
      #pragma unroll
      for (int r = 0; r < 4; ++r) {
        int gm = bm + wr * (MF * 16) + mf * 16 + g * 4 + r;
        int gn = bn + wc * (NF * 16) + nf * 16 + li;
        if (F32OUT) Cf[(size_t)gm * N + gn] = acc[mf][nf][r];
        else        Cb[(size_t)gm * N + gn] = f2bf(acc[mf][nf][r]);
      }
}

// ---------------- flash attention + fused PMSNorm (split-k, balanced) ----------------
// Unchanged from r5-r8.
__global__ __launch_bounds__(512, 2) void attn_kernel(
    const u16* __restrict__ qkv, const u16* __restrict__ Vt,
    const float* __restrict__ nw, u16* __restrict__ Mrg) {
  __shared__ __align__(16) char smem[106496];       // 104 KiB
  char* sKb = smem;
  char* sVb = smem + 65536;
  char* sPb = smem + 65536 + 32768;
  float* oex  = (float*)smem;
  float* mlex = (float*)(smem + 65536);

  const int c = blockIdx.x;
  const int bh = c & 15, iu = c >> 4;
  const int b = bh >> 3, h = bh & 7;
  const int tid = threadIdx.x, lane = tid & 63, w = tid >> 6;
  const int kh = w >> 2, wq = w & 3;
  const int g = lane >> 4, li = lane & 15;
  const float MASKV = -30000.0f;
  const float MINIT = -1000.0f;
  const float isc = 1.0f / 64.0f; // 1 / (sqrt(256) * (LAYER_IDX+1))
  const f32x4 fz = {0.f, 0.f, 0.f, 0.f};
  const size_t KADV = (size_t)32 * 6144 * 2;

  #pragma unroll 1
  for (int uu = 0; uu < 2; ++uu) {
    const int qt = uu ? (31 - iu) : iu;
    const int nt = qt + 1;
    const int kvb0 = kh * nt * 32;

    int qrow = qt * 64 + wq * 16 + li;
    const u16* qp = qkv + (size_t)(b * 2048 + qrow) * 6144 + h * 256;
    bf16x8 qf[8];
    #pragma unroll
    for (int c8 = 0; c8 < 8; ++c8) qf[c8] = ld8(qp + c8 * 32 + g * 8);

    const char* kSrc[4]; u32 kDoff[4];
    #pragma unroll
    for (int j = 0; j < 4; ++j) {
      int chunk = wq * 4 + j;
      int o = chunk * 1024 + lane * 16;
      int row = o >> 9, cb = o & 511;
      int cbs = cb ^ ((row & 7) << 4);
      kSrc[j] = (const char*)qkv + ((size_t)(b * 2048 + kvb0 + row) * 6144 + 2048 + h * 256) * 2 + cbs;
      kDoff[j] = chunk * 1024;
    }
    const char* vSrc[4]; char* vDst[4];
    #pragma unroll
    for (int j = 0; j < 4; ++j) {
      int chunk = wq * 4 + j;
      int o = chunk * 1024 + lane * 16;
      int row = o >> 6, cb = o & 63;
      int cbs = cb ^ (((row >> 1) & 3) << 4);
      vSrc[j] = (const char*)Vt + ((size_t)(bh * 256 + row) * 2048 + kvb0) * 2 + cbs;
      vDst[j] = sVb + kh * 16384 + chunk * 1024;
    }

    f32x4 o_[16];
    #pragma unroll
    for (int nf = 0; nf < 16; ++nf) o_[nf] = fz;
    float m_[4] = {MINIT, MINIT, MINIT, MINIT};
    float l_[4] = {0.f, 0.f, 0.f, 0.f};

    {
      char* kb0 = sKb + (kh * 2 + 0) * 16384;
      #pragma unroll
      for (int j = 0; j < 4; ++j) { g2l16(kSrc[j], kb0 + kDoff[j]); kSrc[j] += KADV; }
    }
    asm volatile("s_waitcnt vmcnt(0)" ::: "memory");
    asm volatile("s_barrier" ::: "memory");

    int cur = 0;
    for (int t = 0; t < nt; ++t) {
      const bool more = (t < nt - 1);
      #pragma unroll
      for (int j = 0; j < 4; ++j) { g2l16(vSrc[j], vDst[j]); vSrc[j] += 64; }
      if (more) {
        char* kb = sKb + (kh * 2 + (cur ^ 1)) * 16384;
        #pragma unroll
        for (int j = 0; j < 4; ++j) { g2l16(kSrc[j], kb + kDoff[j]); kSrc[j] += KADV; }
      }

      f32x4 sacc[2];
      const char* kbase = sKb + (kh * 2 + cur) * 16384;
      __builtin_amdgcn_s_setprio(1);
      #pragma unroll
      for (int nf = 0; nf < 2; ++nf) {
        int row = nf * 16 + li;
        int swz = (row & 7) << 4;
        const char* kr = kbase + row * 512;
        f32x4 sa = fz, sb = fz;
        #pragma unroll
        for (int c8 = 0; c8 < 4; ++c8) {
          sa = __builtin_amdgcn_mfma_f32_16x16x32_bf16(qf[c8],     ld8(kr + ((c8 * 64 + g * 16) ^ swz)),       sa, 0, 0, 0);
          sb = __builtin_amdgcn_mfma_f32_16x16x32_bf16(qf[c8 + 4], ld8(kr + (((c8 + 4) * 64 + g * 16) ^ swz)), sb, 0, 0, 0);
        }
        sacc[nf] = sa + sb;
      }
      __builtin_amdgcn_s_setprio(0);

      const int tidx = kh * nt + t;
      const bool diag = (tidx >= 2 * qt);
      float p[2][4], m0[4];
      #pragma unroll
      for (int r = 0; r < 4; ++r) {
        int qr = qt * 64 + wq * 16 + g * 4 + r;
        float a0 = sacc[0][r] * isc;
        float a1 = sacc[1][r] * isc;
        if (diag) {
          if (tidx * 32 + li > qr) a0 = MASKV;
          if (tidx * 32 + 16 + li > qr) a1 = MASKV;
        }
        p[0][r] = a0; p[1][r] = a1;
        m0[r] = fmaxf(a0, a1);
      }
      bool need = (m0[0] > m_[0] + 8.f) || (m0[1] > m_[1] + 8.f) ||
                  (m0[2] > m_[2] + 8.f) || (m0[3] > m_[3] + 8.f);
      if (__any(need)) {
        #pragma unroll
        for (int r = 0; r < 4; ++r) {
          float mx = m0[r];
          mx = fmaxf(mx, __shfl_xor(mx, 1));
          mx = fmaxf(mx, __shfl_xor(mx, 2));
          mx = fmaxf(mx, __shfl_xor(mx, 4));
          mx = fmaxf(mx, __shfl_xor(mx, 8));
          float mn = fmaxf(m_[r], mx);
          float sc = __expf(m_[r] - mn);
          l_[r] *= sc; m_[r] = mn;
          #pragma unroll
          for (int nf = 0; nf < 16; ++nf) o_[nf][r] *= sc;
        }
      }
      #pragma unroll
      for (int r = 0; r < 4; ++r) {
        float e0 = __expf(p[0][r] - m_[r]);
        float e1 = __expf(p[1][r] - m_[r]);
        p[0][r] = e0; p[1][r] = e1;
        l_[r] += e0 + e1;
      }

      if (more) asm volatile("s_waitcnt vmcnt(4)" ::: "memory");
      else      asm volatile("s_waitcnt vmcnt(0)" ::: "memory");
      asm volatile("s_barrier" ::: "memory");

      char* sPw = sPb + kh * 4096 + wq * 1024;
      #pragma unroll
      for (int r = 0; r < 4; ++r) {
        int row = g * 4 + r;
        int swz = ((row >> 1) & 3) << 4;
        #pragma unroll
        for (int nf = 0; nf < 2; ++nf)
          *(u16*)(sPw + row * 64 + (((nf * 16 + li) * 2) ^ swz)) = f2bf(p[nf][r]);
      }
      asm volatile("s_waitcnt lgkmcnt(0)" ::: "memory");
      __builtin_amdgcn_sched_barrier(0);

      __builtin_amdgcn_s_setprio(1);
      {
        const char* vb = sVb + kh * 16384;
        bf16x8 pa = ld8(sPw + li * 64 + ((g * 16) ^ (((li >> 1) & 3) << 4)));
        #pragma unroll
        for (int nf = 0; nf < 16; ++nf) {
          int row = nf * 16 + li;
          bf16x8 vf = ld8(vb + row * 64 + ((g * 16) ^ (((row >> 1) & 3) << 4)));
          o_[nf] = __builtin_amdgcn_mfma_f32_16x16x32_bf16(pa, vf, o_[nf], 0, 0, 0);
        }
      }
      __builtin_amdgcn_s_setprio(0);

      asm volatile("s_barrier" ::: "memory");
      if (more) asm volatile("s_waitcnt vmcnt(0)" ::: "memory");
      cur ^= 1;
    }

    if (kh == 1) {
      #pragma unroll
      for (int nf = 0; nf < 16; ++nf)
        *(f32x4*)(oex + wq * 4096 + nf * 256 + lane * 4) = o_[nf];
      #pragma unroll
      for (int r = 0; r < 4; ++r) {
        mlex[wq * 512 + r * 64 + lane] = l_[r];
        mlex[wq * 512 + 256 + r * 64 + lane] = m_[r];
      }
    }
    __syncthreads();
    if (kh == 0) {
      float aw[4], bw[4], inv_l[4];
      #pragma unroll
      for (int r = 0; r < 4; ++r) {
        float mB = mlex[wq * 512 + 256 + r * 64 + lane];
        float lB = mlex[wq * 512 + r * 64 + lane];
        float mm = fmaxf(m_[r], mB);
        aw[r] = __expf(m_[r] - mm);
        bw[r] = __expf(mB - mm);
        float lr = l_[r] * aw[r] + lB * bw[r];
        lr += __shfl_xor(lr, 1);
        lr += __shfl_xor(lr, 2);
        lr += __shfl_xor(lr, 4);
        lr += __shfl_xor(lr, 8);
        inv_l[r] = 1.0f / lr;
      }
      #pragma unroll
      for (int nf = 0; nf < 16; ++nf) {
        f32x4 ob = *(f32x4*)(oex + wq * 4096 + nf * 256 + lane * 4);
        #pragma unroll
        for (int r = 0; r < 4; ++r)
          o_[nf][r] = o_[nf][r] * aw[r] + ob[r] * bw[r];
      }
      #pragma unroll
      for (int r = 0; r < 4; ++r) {
        float ss = 0.f;
        #pragma unroll
        for (int nf = 0; nf < 16; ++nf) {
          float v = o_[nf][r] * inv_l[r];
          ss += v * v;
        }
        ss += __shfl_xor(ss, 1);
        ss += __shfl_xor(ss, 2);
        ss += __shfl_xor(ss, 4);
        ss += __shfl_xor(ss, 8);
        float rms = rsqrtf(ss * (1.0f / 256.0f) + 1e-5f);
        int row = qt * 64 + wq * 16 + g * 4 + r;
        #pragma unroll
        for (int nf = 0; nf < 16; ++nf) {
          int d = nf * 16 + li;
          float v = o_[nf][r] * inv_l[r] * rms * nw[d];
          Mrg[((size_t)(b * 2048 + row)) * 2048 + h * 256 + d] = f2bf(v);
        }
      }
    }
    __syncthreads();
  }
}

extern "C" void kernel_launch(void* const* d_in, const int* in_sizes, int n_in,
                              void* d_out, int out_size, void* d_ws, size_t ws_size,
                              hipStream_t stream) {
  const float* hs  = (const float*)d_in[0];   // [2,2048,2048]
  const float* wat = (const float*)d_in[1];   // [2048,6144]
  const float* wpr = (const float*)d_in[2];   // [2048,2048]
  const float* nw  = (const float*)d_in[3];   // [256]
  float* out = (float*)d_out;                 // [2,2048,2048] f32

  char* ws = (char*)d_ws;
  u16* Xb   = (u16*)(ws + 0);                    // 16 MiB  [4096][2048] bf16
  u16* Wp_t = (u16*)(ws + (16u << 20));          //  8 MiB  [2048][2048] bf16 (w_proj^T)
  u16* Qkv  = (u16*)(ws + (24u << 20));          // 48 MiB  [4096][6144] bf16
  u16* Vt   = (u16*)(ws + (72u << 20));          // 16 MiB  [16][256][2048] bf16
  u16* Mrg  = Xb;                                // aliases Xb (dead after GEMM1)
  u16* Wa_t = (u16*)d_out;                       // 24 MiB scratch (w_attn^T [6144][2048])

  dim3 t328(32, 8);
  cast_bf16_kernel<<<4096, 256, 0, stream>>>(hs, Xb, 1048576);
  tcast_kernel<<<dim3(192, 64), t328, 0, stream>>>(wat, Wa_t, 2048, 6144);
  tcast_kernel<<<dim3(64, 64), t328, 0, stream>>>(wpr, Wp_t, 2048, 2048);
  // qkv: 128x192 tile -> grid 32x32 = 1024 blocks = 2 exact rounds at 2 blocks/CU
  gemm2b_kernel<2, 4, 4, 3, false><<<dim3(32, 32), 512, 0, stream>>>(
      Xb, Wa_t, nullptr, Qkv, 4096, 6144, 2048);
  tv_kernel<<<dim3(8, 64, 16), t328, 0, stream>>>(Qkv, Vt);
  attn_kernel<<<256, 512, 0, stream>>>(Qkv, Vt, nw, Mrg);
  // proj: 128x128 tile -> grid 16x32 = 512 blocks = 1 exact round at 2 blocks/CU
  gemm2b_kernel<2, 4, 4, 2, true><<<dim3(16, 32), 512, 0, stream>>>(
      Mrg, Wp_t, out, nullptr, 4096, 2048, 2048);
  (void)in_sizes; (void)n_in; (void)out_size; (void)ws_size;
}